// Round 4
// baseline (5275.407 us; speedup 1.0000x reference)
//
#include <hip/hip_runtime.h>

#define BB 100000
#define NN 20
#define ND 128
#define TD 64
#define CD 192
#define HD 128
#define NH 4
#define DH 32
#define NL 2
#define G 4
#define T 512
#define KCS 196   // padded kc row stride (bf16 elements): 392B rows, 8B aligned
#define RUS 772   // padded r/u row stride (floats): 16B aligned, banks spread

static_assert(BB % G == 0, "grid must divide B");

static __device__ __forceinline__ float bf2f(unsigned short u) {
  return __uint_as_float(((unsigned)u) << 16);
}
static __device__ __forceinline__ unsigned short f2bf(float x) {
  unsigned b = __float_as_uint(x);
  return (unsigned short)((b + 0x7FFFu + ((b >> 16) & 1u)) >> 16);
}

// scores_h(n) = q_h . (kcomb_n @ Wk_h)  with q = qcomb@Wq + bq.
// (bk contributes an n-uniform shift -> softmax-invariant -> dropped.)
// Rank-32 factorization: r_h = q_h @ Wk_h^T.
// LDS diet for 3 blocks/CU: us aliases rs (rus); ffs aliases rus[:,0:128];
// as_ AND ys alias h1s (as_ = lower 2KB, ys = upper 2KB; all lifetime-disjoint:
// ys lives y->r phase, as_ lives a->attn phase, h1s lives FF1->FF2).
// Raw = 52,176 -> alloc 52,224; 3 x 52,224 = 156,672 (7.2 KB headroom vs the
// reserved-LDS effect that blocked R3's 162,816).
__global__ __launch_bounds__(T, 4) void tgat_fused(
    const float* __restrict__ nf, const float* __restrict__ nbf,
    const float* __restrict__ nt, const float* __restrict__ nbt,
    const float* __restrict__ tf, const float* __restrict__ tp,
    const float* __restrict__ Wq, const float* __restrict__ bq,
    const float* __restrict__ Wk,
    const float* __restrict__ Wv, const float* __restrict__ bv,
    const float* __restrict__ Wo, const float* __restrict__ bo,
    const float* __restrict__ W1, const float* __restrict__ b1,
    const float* __restrict__ W2, const float* __restrict__ b2,
    const float* __restrict__ g1, const float* __restrict__ be1,
    const float* __restrict__ g2, const float* __restrict__ be2,
    const float* __restrict__ Wc1, const float* __restrict__ bc1,
    const float* __restrict__ Wc2, const float* __restrict__ bc2,
    const int* __restrict__ mask,
    float* __restrict__ out) {
  __shared__ __align__(16) unsigned short kc[G][NN][KCS]; // 31,360 B kcomb bf16
  __shared__ __align__(16) float xs[G][ND];               //  2,048 B
  __shared__ __align__(16) float tqs[G][TD];              //  1,024 B
  __shared__ __align__(16) float rus[G][RUS];             // 12,352 B r, then u, then ff
  __shared__ __align__(16) float scs[G][NH][NN];          //  1,280 B
  __shared__ __align__(16) float h1s[G][2 * ND];          //  4,096 B (as_/ys alias)
  __shared__ __align__(16) unsigned msks[G];              //     16 B bitmask

  float* asv = &h1s[0][0];            // as_[g][j] == asv[g*HD+j]   (lower 2 KB)
  float* ysv = &h1s[0][0] + G * HD;   // ys[g][j]  == ysv[g*HD+j]   (upper 2 KB)

  const int tid = threadIdx.x;
  const int b0 = blockIdx.x * G;

  // ---- stage per-element data (once; reused by both layers) ----
  for (int idx = tid; idx < G * ND; idx += T) {
    int g = idx >> 7, j = idx & 127;
    xs[g][j] = nf[(b0 + g) * ND + j];
  }
  for (int idx = tid; idx < G * TD; idx += T) {
    int g = idx >> 6, j = idx & 63;
    tqs[g][j] = __cosf(nt[b0 + g] * tf[j] + tp[j]);
  }
  if (tid < G) {
    unsigned m = 0;
    for (int n = 0; n < NN; ++n)
      m |= (mask[(b0 + tid) * NN + n] != 0 ? 1u : 0u) << n;
    msks[tid] = m;
  }
  // neighbor features -> kc (vectorized float4 -> ushort4)
  for (int idx = tid; idx < G * NN * (ND / 4); idx += T) {
    int g = idx / (NN * (ND / 4));
    int rem = idx % (NN * (ND / 4));
    int n = rem >> 5, cq = rem & 31;
    float4 v = *(const float4*)&nbf[(((b0 + g) * NN + n) * ND) + cq * 4];
    ushort4 o;
    o.x = f2bf(v.x); o.y = f2bf(v.y); o.z = f2bf(v.z); o.w = f2bf(v.w);
    *(ushort4*)&kc[g][n][cq * 4] = o;
  }
  for (int idx = tid; idx < G * NN * TD; idx += T) {
    int g = idx / (NN * TD), rem = idx % (NN * TD);
    int n = rem >> 6, j = rem & 63;
    kc[g][n][ND + j] = f2bf(__cosf(nbt[(b0 + g) * NN + n] * tf[j] + tp[j]));
  }
  __syncthreads();

  const float scale = 0.17677669529663687f; // 1/sqrt(32)

  for (int l = 0; l < NL; ++l) {
    // ---- y = qcomb @ Wq + bq : exactly one output per thread (into ysv) ----
    {
      int g = tid >> 7, j = tid & 127;
      const float* wq = Wq + (l * CD) * HD + j;
      float acc = bq[l * HD + j];
      for (int c = 0; c < CD; c += 4) {
        float4 qv = (c < ND) ? *(const float4*)&xs[g][c]
                             : *(const float4*)&tqs[g][c - ND];
        acc += qv.x * wq[(c + 0) * HD] + qv.y * wq[(c + 1) * HD] +
               qv.z * wq[(c + 2) * HD] + qv.w * wq[(c + 3) * HD];
      }
      ysv[g * HD + j] = acc;
    }
    __syncthreads();
    // ---- r[g][h*CD+c2] = sum_d y[g][h][d] * Wk[c2][h*32+d] ----
    // 768 (h,c2) x 2 g-pairs = 1536 units, 3 per thread (balanced).
    for (int rep = 0; rep < 3; ++rep) {
      int uu = rep * T + tid;       // 0..1535
      int i = uu >> 1;              // 0..767 = h*CD + c2
      int gp = (uu & 1) << 1;       // 0 or 2
      int h = i / CD;
      int c2 = i - h * CD;
      const float* wk = Wk + (l * CD + c2) * HD + h * DH;
      const float* yp0 = &ysv[gp * HD + h * DH];
      const float* yp1 = &ysv[(gp + 1) * HD + h * DH];
      float a0 = 0.f, a1 = 0.f;
#pragma unroll
      for (int d = 0; d < DH; d += 4) {
        float4 w4 = *(const float4*)&wk[d];
        float4 y0 = *(const float4*)&yp0[d];
        float4 y1 = *(const float4*)&yp1[d];
        a0 += y0.x * w4.x + y0.y * w4.y + y0.z * w4.z + y0.w * w4.w;
        a1 += y1.x * w4.x + y1.y * w4.y + y1.z * w4.z + y1.w * w4.w;
      }
      rus[gp][i] = a0;
      rus[gp + 1][i] = a1;
    }
    __syncthreads();
    // ---- scores[g][h][n] = scale * r_h . kcomb_n (masked -> -1e9) ----
    for (int idx = tid; idx < G * NH * NN; idx += T) {
      int g = idx / (NH * NN), rem = idx % (NH * NN);
      int h = rem / NN, n = rem % NN;
      const float* rp = &rus[g][h * CD];
      const unsigned short* kp = &kc[g][n][0];
      float acc = 0.f;
      for (int c = 0; c < CD; c += 4) {
        float4 rv = *(const float4*)&rp[c];
        ushort4 kv = *(const ushort4*)&kp[c];
        acc += rv.x * bf2f(kv.x) + rv.y * bf2f(kv.y) +
               rv.z * bf2f(kv.z) + rv.w * bf2f(kv.w);
      }
      scs[g][h][n] = ((msks[g] >> n) & 1u) ? acc * scale : -1e9f;
    }
    __syncthreads();
    // ---- softmax per (g,h) ----
    if (tid < G * NH) {
      int g = tid / NH, h = tid % NH;
      float mx = -3.4e38f;
#pragma unroll
      for (int n = 0; n < NN; ++n) mx = fmaxf(mx, scs[g][h][n]);
      float ev[NN];
      float s = 0.f;
#pragma unroll
      for (int n = 0; n < NN; ++n) { ev[n] = __expf(scs[g][h][n] - mx); s += ev[n]; }
      float inv = 1.f / s;
#pragma unroll
      for (int n = 0; n < NN; ++n) scs[g][h][n] = ev[n] * inv;
    }
    __syncthreads();
    // ---- u[g][h][c] = sum_n w[g][h][n] * kcomb[g][n][c] : 768 quads ----
    // (overwrites rus; r is dead after scores)
    for (int flat = tid; flat < G * NH * (CD / 4); flat += T) {
      int g = flat / (NH * (CD / 4));
      int iq = flat % (NH * (CD / 4));
      int h = iq / (CD / 4);
      int c = (iq % (CD / 4)) * 4;
      const unsigned short* kp = &kc[g][0][0];
      float a0 = 0.f, a1 = 0.f, a2 = 0.f, a3 = 0.f;
#pragma unroll
      for (int n = 0; n < NN; ++n) {
        float w = scs[g][h][n];
        ushort4 kv = *(const ushort4*)&kp[n * KCS + c];
        a0 += w * bf2f(kv.x); a1 += w * bf2f(kv.y);
        a2 += w * bf2f(kv.z); a3 += w * bf2f(kv.w);
      }
      *(float4*)&rus[g][h * CD + c] = make_float4(a0, a1, a2, a3);
    }
    __syncthreads();
    // ---- a = u @ Wv + bv : one output per thread (into asv, lower h1s) ----
    {
      int j = tid & (HD - 1);
      int g = tid >> 7;
      int h = j >> 5;
      const float* wv = Wv + (l * CD) * HD + j;
      float acc = 0.f;
      for (int c = 0; c < CD; c += 4) {
        float4 uv = *(const float4*)&rus[g][h * CD + c];
        acc += uv.x * wv[(c + 0) * HD] + uv.y * wv[(c + 1) * HD] +
               uv.z * wv[(c + 2) * HD] + uv.w * wv[(c + 3) * HD];
      }
      asv[g * HD + j] = acc + bv[l * HD + j];
    }
    __syncthreads();
    // ---- attn = a @ Wo + bo -> ffs (= rus[g][0:128]; u dead now) ----
    {
      int j = tid & (ND - 1);
      int g = tid >> 7;
      const float* wo = Wo + (l * HD) * ND + j;
      float acc = 0.f;
      for (int c = 0; c < HD; c += 4) {
        float4 av = *(const float4*)&asv[g * HD + c];
        acc += av.x * wo[(c + 0) * ND] + av.y * wo[(c + 1) * ND] +
               av.z * wo[(c + 2) * ND] + av.w * wo[(c + 3) * ND];
      }
      rus[g][j] = acc + bo[l * ND + j];
    }
    __syncthreads();
    // ---- LN1: wave g (of first 4 waves) owns element g ----
    if (tid < G * 64) {
      int g = tid >> 6, lane = tid & 63;
      float y0 = xs[g][lane] + rus[g][lane];
      float y1 = xs[g][lane + 64] + rus[g][lane + 64];
      float s = y0 + y1, ss = y0 * y0 + y1 * y1;
#pragma unroll
      for (int off = 32; off > 0; off >>= 1) {
        s += __shfl_xor(s, off);
        ss += __shfl_xor(ss, off);
      }
      float mean = s * (1.f / ND);
      float var = ss * (1.f / ND) - mean * mean;
      float rstd = rsqrtf(var + 1e-5f);
      xs[g][lane] = (y0 - mean) * rstd * g1[l * ND + lane] + be1[l * ND + lane];
      xs[g][lane + 64] =
          (y1 - mean) * rstd * g1[l * ND + lane + 64] + be1[l * ND + lane + 64];
    }
    __syncthreads();
    // ---- FF1: h1 = relu(x @ W1 + b1) : 2 outputs per thread ----
    // (overwrites all of h1s; asv/ysv dead now)
    {
      int j = tid & (2 * ND - 1);
      int gq = tid >> 8;  // 0..1, handles g = gq and gq+2
      const float* w1p = W1 + (l * ND) * (2 * ND) + j;
      float acc0 = 0.f, acc1 = 0.f;
      for (int c = 0; c < ND; c += 4) {
        float w0 = w1p[(c + 0) * 2 * ND], wa = w1p[(c + 1) * 2 * ND],
              w2 = w1p[(c + 2) * 2 * ND], w3 = w1p[(c + 3) * 2 * ND];
        float4 x0 = *(const float4*)&xs[gq][c];
        float4 x1 = *(const float4*)&xs[gq + 2][c];
        acc0 += x0.x * w0 + x0.y * wa + x0.z * w2 + x0.w * w3;
        acc1 += x1.x * w0 + x1.y * wa + x1.z * w2 + x1.w * w3;
      }
      float b1v = b1[l * 2 * ND + j];
      h1s[gq][j] = fmaxf(acc0 + b1v, 0.f);
      h1s[gq + 2][j] = fmaxf(acc1 + b1v, 0.f);
    }
    __syncthreads();
    // ---- FF2 -> ffs (= rus[g][0:128]) : one output per thread ----
    {
      int j = tid & (ND - 1);
      int g = tid >> 7;
      const float* w2p = W2 + (l * 2 * ND) * ND + j;
      float acc = 0.f;
      for (int c = 0; c < 2 * ND; c += 4) {
        float4 hv = *(const float4*)&h1s[g][c];
        acc += hv.x * w2p[(c + 0) * ND] + hv.y * w2p[(c + 1) * ND] +
               hv.z * w2p[(c + 2) * ND] + hv.w * w2p[(c + 3) * ND];
      }
      rus[g][j] = acc + b2[l * ND + j];
    }
    __syncthreads();
    // ---- LN2 ----
    if (tid < G * 64) {
      int g = tid >> 6, lane = tid & 63;
      float y0 = xs[g][lane] + rus[g][lane];
      float y1 = xs[g][lane + 64] + rus[g][lane + 64];
      float s = y0 + y1, ss = y0 * y0 + y1 * y1;
#pragma unroll
      for (int off = 32; off > 0; off >>= 1) {
        s += __shfl_xor(s, off);
        ss += __shfl_xor(ss, off);
      }
      float mean = s * (1.f / ND);
      float var = ss * (1.f / ND) - mean * mean;
      float rstd = rsqrtf(var + 1e-5f);
      xs[g][lane] = (y0 - mean) * rstd * g2[l * ND + lane] + be2[l * ND + lane];
      xs[g][lane + 64] =
          (y1 - mean) * rstd * g2[l * ND + lane + 64] + be2[l * ND + lane + 64];
    }
    __syncthreads();
  }
  // ---- classifier: relu(x@Wc1+bc1) in scs scratch, then sigmoid(h@Wc2+bc2) ----
  if (tid < G * 64) {
    int j = tid & 63;
    int g = tid >> 6;
    const float* wc = Wc1 + j;
    float acc = 0.f;
    for (int c = 0; c < ND; c += 4) {
      float4 xv = *(const float4*)&xs[g][c];
      acc += xv.x * wc[(c + 0) * 64] + xv.y * wc[(c + 1) * 64] +
             xv.z * wc[(c + 2) * 64] + xv.w * wc[(c + 3) * 64];
    }
    ((float*)scs)[g * 64 + j] = fmaxf(acc + bc1[j], 0.f);
  }
  __syncthreads();
  if (tid < G * 64) {
    int g = tid >> 6, lane = tid & 63;
    float p = ((float*)scs)[g * 64 + lane] * Wc2[lane];
#pragma unroll
    for (int off = 32; off > 0; off >>= 1) p += __shfl_xor(p, off);
    if (lane == 0) {
      float z = p + bc2[0];
      out[b0 + g] = 1.f / (1.f + expf(-z));
    }
  }
}

extern "C" void kernel_launch(void* const* d_in, const int* in_sizes, int n_in,
                              void* d_out, int out_size, void* d_ws, size_t ws_size,
                              hipStream_t stream) {
  (void)in_sizes; (void)n_in; (void)out_size; (void)d_ws; (void)ws_size;
  const float* nf  = (const float*)d_in[0];
  const float* nbf = (const float*)d_in[1];
  const float* nt  = (const float*)d_in[2];
  const float* nbt = (const float*)d_in[3];
  const float* tf  = (const float*)d_in[4];
  const float* tp  = (const float*)d_in[5];
  const float* Wq  = (const float*)d_in[6];
  const float* bq  = (const float*)d_in[7];
  const float* Wk  = (const float*)d_in[8];
  // d_in[9] = bk: only contributes n-uniform score shifts -> softmax-invariant
  const float* Wv  = (const float*)d_in[10];
  const float* bv  = (const float*)d_in[11];
  const float* Wo  = (const float*)d_in[12];
  const float* bo  = (const float*)d_in[13];
  const float* W1  = (const float*)d_in[14];
  const float* b1  = (const float*)d_in[15];
  const float* W2  = (const float*)d_in[16];
  const float* b2  = (const float*)d_in[17];
  const float* g1  = (const float*)d_in[18];
  const float* be1 = (const float*)d_in[19];
  const float* g2  = (const float*)d_in[20];
  const float* be2 = (const float*)d_in[21];
  const float* Wc1 = (const float*)d_in[22];
  const float* bc1 = (const float*)d_in[23];
  const float* Wc2 = (const float*)d_in[24];
  const float* bc2 = (const float*)d_in[25];
  const int* mask  = (const int*)d_in[26];
  float* out = (float*)d_out;

  tgat_fused<<<BB / G, T, 0, stream>>>(nf, nbf, nt, nbt, tf, tp, Wq, bq, Wk,
                                       Wv, bv, Wo, bo, W1, b1, W2, b2, g1, be1,
                                       g2, be2, Wc1, bc1, Wc2, bc2, mask, out);
}

// Round 5
// 4194.167 us; speedup vs baseline: 1.2578x; 1.2578x over previous
//
#include <hip/hip_runtime.h>

#define BB 100000
#define NN 20
#define ND 128
#define TD 64
#define CD 192
#define HD 128
#define NH 4
#define DH 32
#define NL 2
#define G 2
#define T 256
#define KCS 196   // padded kc row stride (bf16 elements): 392B rows, 8B aligned
#define RUS 772   // padded r/u row stride (floats): 16B aligned, banks spread

static_assert(BB % G == 0, "grid must divide B");

static __device__ __forceinline__ float bf2f(unsigned short u) {
  return __uint_as_float(((unsigned)u) << 16);
}
static __device__ __forceinline__ unsigned short f2bf(float x) {
  unsigned b = __float_as_uint(x);
  return (unsigned short)((b + 0x7FFFu + ((b >> 16) & 1u)) >> 16);
}

// scores_h(n) = q_h . (kcomb_n @ Wk_h)  with q = qcomb@Wq + bq.
// (bk contributes an n-uniform shift -> softmax-invariant -> dropped.)
// Rank-32 factorization: r_h = q_h @ Wk_h^T.
// R3/R4 lesson: 512-thread blocks never co-reside 3x regardless of LDS
// (52-54KB both gave 2 blocks/CU) -> LDS likely split in two 80KB halves.
// G=2/T=256 @ ~27KB LDS fits 3 per half = 6 blocks/CU = 24 waves under the
// partition model (and >=5 blocks under every other model).
// ys kept as a DISTINCT array (R4's ys->h1s alias cost 19%: compiler LDS
// dependence conservatism); asv/rus/ffs aliases retained from R3 (clean).
__global__ __launch_bounds__(T, 4) void tgat_fused(
    const float* __restrict__ nf, const float* __restrict__ nbf,
    const float* __restrict__ nt, const float* __restrict__ nbt,
    const float* __restrict__ tf, const float* __restrict__ tp,
    const float* __restrict__ Wq, const float* __restrict__ bq,
    const float* __restrict__ Wk,
    const float* __restrict__ Wv, const float* __restrict__ bv,
    const float* __restrict__ Wo, const float* __restrict__ bo,
    const float* __restrict__ W1, const float* __restrict__ b1,
    const float* __restrict__ W2, const float* __restrict__ b2,
    const float* __restrict__ g1, const float* __restrict__ be1,
    const float* __restrict__ g2, const float* __restrict__ be2,
    const float* __restrict__ Wc1, const float* __restrict__ bc1,
    const float* __restrict__ Wc2, const float* __restrict__ bc2,
    const int* __restrict__ mask,
    float* __restrict__ out) {
  __shared__ __align__(16) unsigned short kc[G][NN][KCS]; // 15,680 B kcomb bf16
  __shared__ __align__(16) float xs[G][ND];               //  1,024 B
  __shared__ __align__(16) float tqs[G][TD];              //    512 B
  __shared__ __align__(16) float ys[G][HD];               //  1,024 B q proj
  __shared__ __align__(16) float rus[G][RUS];             //  6,176 B r, then u, then ff
  __shared__ __align__(16) float scs[G][NH][NN];          //    640 B
  __shared__ __align__(16) float h1s[G][2 * ND];          //  2,048 B (as_ aliases h1s[0])
  __shared__ __align__(16) unsigned msks[G];              //      8 B bitmask
  // raw total 27,112 -> alloc 27,136

  float* asv = &h1s[0][0];  // as_[g][j] == asv[g*HD+j]; dead before FF1 writes h1s

  const int tid = threadIdx.x;
  const int b0 = blockIdx.x * G;

  // ---- stage per-element data (once; reused by both layers) ----
  {
    int g = tid >> 7, j = tid & 127;  // G*ND = 256 = 1/thread
    xs[g][j] = nf[(b0 + g) * ND + j];
  }
  if (tid < G * TD) {
    int g = tid >> 6, j = tid & 63;
    tqs[g][j] = __cosf(nt[b0 + g] * tf[j] + tp[j]);
  }
  if (tid < G) {
    unsigned m = 0;
    for (int n = 0; n < NN; ++n)
      m |= (mask[(b0 + tid) * NN + n] != 0 ? 1u : 0u) << n;
    msks[tid] = m;
  }
  // neighbor features -> kc (vectorized float4 -> ushort4): 1280 quads
  for (int idx = tid; idx < G * NN * (ND / 4); idx += T) {
    int g = idx / (NN * (ND / 4));
    int rem = idx % (NN * (ND / 4));
    int n = rem >> 5, cq = rem & 31;
    float4 v = *(const float4*)&nbf[(((b0 + g) * NN + n) * ND) + cq * 4];
    ushort4 o;
    o.x = f2bf(v.x); o.y = f2bf(v.y); o.z = f2bf(v.z); o.w = f2bf(v.w);
    *(ushort4*)&kc[g][n][cq * 4] = o;
  }
  for (int idx = tid; idx < G * NN * TD; idx += T) {
    int g = idx / (NN * TD), rem = idx % (NN * TD);
    int n = rem >> 6, j = rem & 63;
    kc[g][n][ND + j] = f2bf(__cosf(nbt[(b0 + g) * NN + n] * tf[j] + tp[j]));
  }
  __syncthreads();

  const float scale = 0.17677669529663687f; // 1/sqrt(32)

  for (int l = 0; l < NL; ++l) {
    // ---- y = qcomb @ Wq + bq : exactly one output per thread ----
    {
      int g = tid >> 7, j = tid & 127;
      const float* wq = Wq + (l * CD) * HD + j;
      float acc = bq[l * HD + j];
      for (int c = 0; c < CD; c += 4) {
        float4 qv = (c < ND) ? *(const float4*)&xs[g][c]
                             : *(const float4*)&tqs[g][c - ND];
        acc += qv.x * wq[(c + 0) * HD] + qv.y * wq[(c + 1) * HD] +
               qv.z * wq[(c + 2) * HD] + qv.w * wq[(c + 3) * HD];
      }
      ys[g][j] = acc;
    }
    __syncthreads();
    // ---- r[g][h*CD+c2] = sum_d y[g][h][d] * Wk[c2][h*32+d] ----
    // 768 (h,c2) units, both g per unit -> 3 per thread.
    for (int rep = 0; rep < 3; ++rep) {
      int i = rep * T + tid;        // 0..767 = h*CD + c2
      int h = i / CD;
      int c2 = i - h * CD;
      const float* wk = Wk + (l * CD + c2) * HD + h * DH;
      const float* yp0 = &ys[0][h * DH];
      const float* yp1 = &ys[1][h * DH];
      float a0 = 0.f, a1 = 0.f;
#pragma unroll
      for (int d = 0; d < DH; d += 4) {
        float4 w4 = *(const float4*)&wk[d];
        float4 y0 = *(const float4*)&yp0[d];
        float4 y1 = *(const float4*)&yp1[d];
        a0 += y0.x * w4.x + y0.y * w4.y + y0.z * w4.z + y0.w * w4.w;
        a1 += y1.x * w4.x + y1.y * w4.y + y1.z * w4.z + y1.w * w4.w;
      }
      rus[0][i] = a0;
      rus[1][i] = a1;
    }
    __syncthreads();
    // ---- scores[g][h][n] = scale * r_h . kcomb_n (masked -> -1e9) ----
    if (tid < G * NH * NN) {
      int g = tid / (NH * NN), rem = tid % (NH * NN);
      int h = rem / NN, n = rem % NN;
      const float* rp = &rus[g][h * CD];
      const unsigned short* kp = &kc[g][n][0];
      float acc = 0.f;
      for (int c = 0; c < CD; c += 4) {
        float4 rv = *(const float4*)&rp[c];
        ushort4 kv = *(const ushort4*)&kp[c];
        acc += rv.x * bf2f(kv.x) + rv.y * bf2f(kv.y) +
               rv.z * bf2f(kv.z) + rv.w * bf2f(kv.w);
      }
      scs[g][h][n] = ((msks[g] >> n) & 1u) ? acc * scale : -1e9f;
    }
    __syncthreads();
    // ---- softmax per (g,h) ----
    if (tid < G * NH) {
      int g = tid / NH, h = tid % NH;
      float mx = -3.4e38f;
#pragma unroll
      for (int n = 0; n < NN; ++n) mx = fmaxf(mx, scs[g][h][n]);
      float ev[NN];
      float s = 0.f;
#pragma unroll
      for (int n = 0; n < NN; ++n) { ev[n] = __expf(scs[g][h][n] - mx); s += ev[n]; }
      float inv = 1.f / s;
#pragma unroll
      for (int n = 0; n < NN; ++n) scs[g][h][n] = ev[n] * inv;
    }
    __syncthreads();
    // ---- u[g][h][c] = sum_n w[g][h][n] * kcomb[g][n][c] : 384 quads ----
    // (overwrites rus; r is dead after scores)
    for (int flat = tid; flat < G * NH * (CD / 4); flat += T) {
      int g = flat / (NH * (CD / 4));
      int iq = flat % (NH * (CD / 4));
      int h = iq / (CD / 4);
      int c = (iq % (CD / 4)) * 4;
      const unsigned short* kp = &kc[g][0][0];
      float a0 = 0.f, a1 = 0.f, a2 = 0.f, a3 = 0.f;
#pragma unroll
      for (int n = 0; n < NN; ++n) {
        float w = scs[g][h][n];
        ushort4 kv = *(const ushort4*)&kp[n * KCS + c];
        a0 += w * bf2f(kv.x); a1 += w * bf2f(kv.y);
        a2 += w * bf2f(kv.z); a3 += w * bf2f(kv.w);
      }
      *(float4*)&rus[g][h * CD + c] = make_float4(a0, a1, a2, a3);
    }
    __syncthreads();
    // ---- a = u @ Wv + bv : one output per thread (into asv == h1s[0]) ----
    {
      int j = tid & (HD - 1);
      int g = tid >> 7;
      int h = j >> 5;
      const float* wv = Wv + (l * CD) * HD + j;
      float acc = 0.f;
      for (int c = 0; c < CD; c += 4) {
        float4 uv = *(const float4*)&rus[g][h * CD + c];
        acc += uv.x * wv[(c + 0) * HD] + uv.y * wv[(c + 1) * HD] +
               uv.z * wv[(c + 2) * HD] + uv.w * wv[(c + 3) * HD];
      }
      asv[g * HD + j] = acc + bv[l * HD + j];
    }
    __syncthreads();
    // ---- attn = a @ Wo + bo -> ffs (= rus[g][0:128]; u dead now) ----
    {
      int j = tid & (ND - 1);
      int g = tid >> 7;
      const float* wo = Wo + (l * HD) * ND + j;
      float acc = 0.f;
      for (int c = 0; c < HD; c += 4) {
        float4 av = *(const float4*)&asv[g * HD + c];
        acc += av.x * wo[(c + 0) * ND] + av.y * wo[(c + 1) * ND] +
               av.z * wo[(c + 2) * ND] + av.w * wo[(c + 3) * ND];
      }
      rus[g][j] = acc + bo[l * ND + j];
    }
    __syncthreads();
    // ---- LN1: first 2 waves, wave g owns element g ----
    if (tid < G * 64) {
      int g = tid >> 6, lane = tid & 63;
      float y0 = xs[g][lane] + rus[g][lane];
      float y1 = xs[g][lane + 64] + rus[g][lane + 64];
      float s = y0 + y1, ss = y0 * y0 + y1 * y1;
#pragma unroll
      for (int off = 32; off > 0; off >>= 1) {
        s += __shfl_xor(s, off);
        ss += __shfl_xor(ss, off);
      }
      float mean = s * (1.f / ND);
      float var = ss * (1.f / ND) - mean * mean;
      float rstd = rsqrtf(var + 1e-5f);
      xs[g][lane] = (y0 - mean) * rstd * g1[l * ND + lane] + be1[l * ND + lane];
      xs[g][lane + 64] =
          (y1 - mean) * rstd * g1[l * ND + lane + 64] + be1[l * ND + lane + 64];
    }
    __syncthreads();
    // ---- FF1: h1 = relu(x @ W1 + b1) : j = tid, both g per thread ----
    // (overwrites h1s; asv dead after attn)
    {
      int j = tid;
      const float* w1p = W1 + (l * ND) * (2 * ND) + j;
      float acc0 = 0.f, acc1 = 0.f;
      for (int c = 0; c < ND; c += 4) {
        float w0 = w1p[(c + 0) * 2 * ND], wa = w1p[(c + 1) * 2 * ND],
              w2 = w1p[(c + 2) * 2 * ND], w3 = w1p[(c + 3) * 2 * ND];
        float4 x0 = *(const float4*)&xs[0][c];
        float4 x1 = *(const float4*)&xs[1][c];
        acc0 += x0.x * w0 + x0.y * wa + x0.z * w2 + x0.w * w3;
        acc1 += x1.x * w0 + x1.y * wa + x1.z * w2 + x1.w * w3;
      }
      float b1v = b1[l * 2 * ND + j];
      h1s[0][j] = fmaxf(acc0 + b1v, 0.f);
      h1s[1][j] = fmaxf(acc1 + b1v, 0.f);
    }
    __syncthreads();
    // ---- FF2 -> ffs (= rus[g][0:128]) : one output per thread ----
    {
      int j = tid & (ND - 1);
      int g = tid >> 7;
      const float* w2p = W2 + (l * 2 * ND) * ND + j;
      float acc = 0.f;
      for (int c = 0; c < 2 * ND; c += 4) {
        float4 hv = *(const float4*)&h1s[g][c];
        acc += hv.x * w2p[(c + 0) * ND] + hv.y * w2p[(c + 1) * ND] +
               hv.z * w2p[(c + 2) * ND] + hv.w * w2p[(c + 3) * ND];
      }
      rus[g][j] = acc + b2[l * ND + j];
    }
    __syncthreads();
    // ---- LN2 ----
    if (tid < G * 64) {
      int g = tid >> 6, lane = tid & 63;
      float y0 = xs[g][lane] + rus[g][lane];
      float y1 = xs[g][lane + 64] + rus[g][lane + 64];
      float s = y0 + y1, ss = y0 * y0 + y1 * y1;
#pragma unroll
      for (int off = 32; off > 0; off >>= 1) {
        s += __shfl_xor(s, off);
        ss += __shfl_xor(ss, off);
      }
      float mean = s * (1.f / ND);
      float var = ss * (1.f / ND) - mean * mean;
      float rstd = rsqrtf(var + 1e-5f);
      xs[g][lane] = (y0 - mean) * rstd * g2[l * ND + lane] + be2[l * ND + lane];
      xs[g][lane + 64] =
          (y1 - mean) * rstd * g2[l * ND + lane + 64] + be2[l * ND + lane + 64];
    }
    __syncthreads();
  }
  // ---- classifier: relu(x@Wc1+bc1) in scs scratch, then sigmoid(h@Wc2+bc2) ----
  if (tid < G * 64) {
    int j = tid & 63;
    int g = tid >> 6;
    const float* wc = Wc1 + j;
    float acc = 0.f;
    for (int c = 0; c < ND; c += 4) {
      float4 xv = *(const float4*)&xs[g][c];
      acc += xv.x * wc[(c + 0) * 64] + xv.y * wc[(c + 1) * 64] +
             xv.z * wc[(c + 2) * 64] + xv.w * wc[(c + 3) * 64];
    }
    ((float*)scs)[g * 64 + j] = fmaxf(acc + bc1[j], 0.f);
  }
  __syncthreads();
  if (tid < G * 64) {
    int g = tid >> 6, lane = tid & 63;
    float p = ((float*)scs)[g * 64 + lane] * Wc2[lane];
#pragma unroll
    for (int off = 32; off > 0; off >>= 1) p += __shfl_xor(p, off);
    if (lane == 0) {
      float z = p + bc2[0];
      out[b0 + g] = 1.f / (1.f + expf(-z));
    }
  }
}

extern "C" void kernel_launch(void* const* d_in, const int* in_sizes, int n_in,
                              void* d_out, int out_size, void* d_ws, size_t ws_size,
                              hipStream_t stream) {
  (void)in_sizes; (void)n_in; (void)out_size; (void)d_ws; (void)ws_size;
  const float* nf  = (const float*)d_in[0];
  const float* nbf = (const float*)d_in[1];
  const float* nt  = (const float*)d_in[2];
  const float* nbt = (const float*)d_in[3];
  const float* tf  = (const float*)d_in[4];
  const float* tp  = (const float*)d_in[5];
  const float* Wq  = (const float*)d_in[6];
  const float* bq  = (const float*)d_in[7];
  const float* Wk  = (const float*)d_in[8];
  // d_in[9] = bk: only contributes n-uniform score shifts -> softmax-invariant
  const float* Wv  = (const float*)d_in[10];
  const float* bv  = (const float*)d_in[11];
  const float* Wo  = (const float*)d_in[12];
  const float* bo  = (const float*)d_in[13];
  const float* W1  = (const float*)d_in[14];
  const float* b1  = (const float*)d_in[15];
  const float* W2  = (const float*)d_in[16];
  const float* b2  = (const float*)d_in[17];
  const float* g1  = (const float*)d_in[18];
  const float* be1 = (const float*)d_in[19];
  const float* g2  = (const float*)d_in[20];
  const float* be2 = (const float*)d_in[21];
  const float* Wc1 = (const float*)d_in[22];
  const float* bc1 = (const float*)d_in[23];
  const float* Wc2 = (const float*)d_in[24];
  const float* bc2 = (const float*)d_in[25];
  const int* mask  = (const int*)d_in[26];
  float* out = (float*)d_out;

  tgat_fused<<<BB / G, T, 0, stream>>>(nf, nbf, nt, nbt, tf, tp, Wq, bq, Wk,
                                       Wv, bv, Wo, bo, W1, b1, W2, b2, g1, be1,
                                       g2, be2, Wc1, bc1, Wc2, bc2, mask, out);
}

// Round 6
// 2259.113 us; speedup vs baseline: 2.3352x; 1.8566x over previous
//
#include <hip/hip_runtime.h>

#define BB 100000
#define NN 20
#define ND 128
#define TD 64
#define CD 192
#define HD 128
#define NH 4
#define DH 32
#define NL 2

typedef __attribute__((ext_vector_type(8))) short bf16x8;
typedef __attribute__((ext_vector_type(4))) float f32x4;

static __device__ __forceinline__ float bf2f(unsigned short u) {
  return __uint_as_float(((unsigned)u) << 16);
}
static __device__ __forceinline__ unsigned short f2bf(float x) {
  unsigned b = __float_as_uint(x);
  return (unsigned short)((b + 0x7FFFu + ((b >> 16) & 1u)) >> 16);
}
static __device__ __forceinline__ bf16x8 load_a8(const float* p) {
  float4 a = *(const float4*)p, b = *(const float4*)(p + 4);
  bf16x8 r;
  r[0] = (short)f2bf(a.x); r[1] = (short)f2bf(a.y);
  r[2] = (short)f2bf(a.z); r[3] = (short)f2bf(a.w);
  r[4] = (short)f2bf(b.x); r[5] = (short)f2bf(b.y);
  r[6] = (short)f2bf(b.z); r[7] = (short)f2bf(b.w);
  return r;
}

// ---------------------------------------------------------------------------
// MFMA pipeline. Fragment layouts (16x16x32 bf16):
//   A: row = lane&15, k = (lane>>4)*8 + j  (8 consecutive k -> one dwordx4)
//   B: col = lane&15, k = (lane>>4)*8 + j
//   C: col = lane&15, row = (lane>>4)*4 + reg   [HW-verified, learn_hip m89]
// Weights pre-packed so a B-frag is one coalesced 16B load per lane.
// Per-layer WF layout (u16 units, 512/tile): tiles 0-47 Wq[kt*8+nt],
// 48-95 Wk^T[h*12+nt], 96-143 Wv[h*12+kt*2+nt], 144-175 Wo[kt*8+nt],
// 176-239 W1[kt*16+nt], 240-303 W2[kt*8+nt].  Layer stride 155,648 u16.
// ---------------------------------------------------------------------------

__global__ __launch_bounds__(256) void conv_w(
    const float* __restrict__ Wq, const float* __restrict__ Wk,
    const float* __restrict__ Wv, const float* __restrict__ Wo,
    const float* __restrict__ W1, const float* __restrict__ W2,
    unsigned short* __restrict__ WF) {
  int t = blockIdx.x;
  int l = t / 304, tt = t % 304;
#pragma unroll
  for (int e = 0; e < 2; ++e) {
    int idx = threadIdx.x * 2 + e;      // 0..511 element within tile
    int lane = idx >> 3, j = idx & 7;
    int wk = ((lane >> 4) << 3) + j;    // within-tile k 0..31
    int c16 = lane & 15;
    float v;
    if (tt < 48) {                      // Wq [192x128]
      int kt = tt >> 3, n2 = tt & 7;
      v = Wq[((size_t)l * CD + kt * 32 + wk) * HD + n2 * 16 + c16];
    } else if (tt < 96) {               // Wk^T per head [32x192]
      int t2 = tt - 48; int h = t2 / 12, n2 = t2 % 12;
      v = Wk[((size_t)l * CD + n2 * 16 + c16) * HD + h * 32 + wk];
    } else if (tt < 144) {              // Wv per head [192x32]
      int t2 = tt - 96; int h = t2 / 12, r2 = t2 % 12, kt = r2 >> 1, n2 = r2 & 1;
      v = Wv[((size_t)l * CD + kt * 32 + wk) * HD + h * 32 + n2 * 16 + c16];
    } else if (tt < 176) {              // Wo [128x128]
      int t2 = tt - 144; int kt = t2 >> 3, n2 = t2 & 7;
      v = Wo[((size_t)l * HD + kt * 32 + wk) * ND + n2 * 16 + c16];
    } else if (tt < 240) {              // W1 [128x256]
      int t2 = tt - 176; int kt = t2 >> 4, n2 = t2 & 15;
      v = W1[((size_t)l * ND + kt * 32 + wk) * (2 * ND) + n2 * 16 + c16];
    } else {                            // W2 [256x128]
      int t2 = tt - 240; int kt = t2 >> 3, n2 = t2 & 7;
      v = W2[((size_t)l * 2 * ND + kt * 32 + wk) * ND + n2 * 16 + c16];
    }
    WF[(size_t)l * 155648 + (size_t)tt * 512 + idx] = f2bf(v);
  }
}

__global__ __launch_bounds__(256) void prep_tq(
    const float* __restrict__ ntime, const float* __restrict__ tf,
    const float* __restrict__ tp, float* __restrict__ tqf) {
  int i = blockIdx.x * 256 + threadIdx.x;  // 0..6.4M
  int b = i >> 6, j = i & 63;
  tqf[i] = __cosf(ntime[b] * tf[j] + tp[j]);
}

// Generic 16-row-block GEMM: C[m][seg*cColMul + n] (+bias)(+relu) f32.
// TN tiles per wave (wave count = blockDim/64). A f32 (bf16-rounded at load);
// optional concat source A2 for k >= ksplit (y's [x|tq]).
template <int TN>
__global__ __launch_bounds__(256) void gemm16(
    const float* __restrict__ A, int lda,
    const float* __restrict__ A2, int lda2, int ksplit,
    const unsigned short* __restrict__ BF,
    int ktiles, int ntiles, int aKoffMul, int cColMul, int segBMul,
    const float* __restrict__ bias,
    float* __restrict__ C, int ldc, int relu) {
  const int tid = threadIdx.x;
  const int wv = tid >> 6, lane = tid & 63;
  const int NW = blockDim.x >> 6;
  const int m0 = blockIdx.x << 4;
  const int seg = blockIdx.y;
  const int arow = m0 + (lane & 15);
  const int kgrp = (lane >> 4) << 3;
  const int aK = seg * aKoffMul;
  const unsigned short* Bseg = BF + (size_t)seg * segBMul * 512;
  f32x4 acc[TN];
#pragma unroll
  for (int i = 0; i < TN; ++i) acc[i] = f32x4{0.f, 0.f, 0.f, 0.f};
  for (int kt = 0; kt < ktiles; ++kt) {
    const float* ap;
    if (kt * 32 >= ksplit)
      ap = A2 + (size_t)arow * lda2 + (kt * 32 - ksplit) + kgrp;
    else
      ap = A + (size_t)arow * lda + aK + kt * 32 + kgrp;
    bf16x8 af = load_a8(ap);
#pragma unroll
    for (int i = 0; i < TN; ++i) {
      int nt = wv + NW * i;
      bf16x8 bf = *(const bf16x8*)(Bseg + (((size_t)(kt * ntiles + nt)) << 9) +
                                   (lane << 3));
      acc[i] = __builtin_amdgcn_mfma_f32_16x16x32_bf16(af, bf, acc[i], 0, 0, 0);
    }
  }
  const int crow = m0 + ((lane >> 4) << 2);
#pragma unroll
  for (int i = 0; i < TN; ++i) {
    int nt = wv + NW * i;
    int col = seg * cColMul + nt * 16 + (lane & 15);
    float bv = bias ? bias[col] : 0.f;
#pragma unroll
    for (int rr = 0; rr < 4; ++rr) {
      float v = acc[i][rr] + bv;
      if (relu) v = fmaxf(v, 0.f);
      C[(size_t)(crow + rr) * ldc + col] = v;
    }
  }
}

// GEMM (N=128 fixed) + bias + residual + LayerNorm fused epilogue -> xout f32.
// In-place res==xout is safe: each thread reads exactly what it later writes.
__global__ __launch_bounds__(256) void gemm_ln(
    const float* __restrict__ A, int lda, int ktiles,
    const unsigned short* __restrict__ BF,
    const float* __restrict__ bias, const float* __restrict__ res,
    const float* __restrict__ gamma, const float* __restrict__ beta,
    float* __restrict__ xout) {
  __shared__ float Cs[16][132];
  const int tid = threadIdx.x;
  const int wv = tid >> 6, lane = tid & 63;
  const int m0 = blockIdx.x << 4;
  const int arow = m0 + (lane & 15);
  const int kgrp = (lane >> 4) << 3;
  const int nt0 = wv, nt1 = wv + 4;
  f32x4 acc0 = {0.f, 0.f, 0.f, 0.f}, acc1 = {0.f, 0.f, 0.f, 0.f};
  for (int kt = 0; kt < ktiles; ++kt) {
    bf16x8 af = load_a8(A + (size_t)arow * lda + kt * 32 + kgrp);
    bf16x8 b0 = *(const bf16x8*)(BF + (((size_t)(kt * 8 + nt0)) << 9) + (lane << 3));
    bf16x8 b1 = *(const bf16x8*)(BF + (((size_t)(kt * 8 + nt1)) << 9) + (lane << 3));
    acc0 = __builtin_amdgcn_mfma_f32_16x16x32_bf16(af, b0, acc0, 0, 0, 0);
    acc1 = __builtin_amdgcn_mfma_f32_16x16x32_bf16(af, b1, acc1, 0, 0, 0);
  }
  {
    const int lrow = (lane >> 4) << 2;
    int c0 = nt0 * 16 + (lane & 15), c1 = nt1 * 16 + (lane & 15);
    float bv0 = bias[c0], bv1 = bias[c1];
#pragma unroll
    for (int rr = 0; rr < 4; ++rr) {
      Cs[lrow + rr][c0] = acc0[rr] + bv0;
      Cs[lrow + rr][c1] = acc1[rr] + bv1;
    }
  }
  __syncthreads();
#pragma unroll
  for (int rr = 0; rr < 4; ++rr) {
    int rw = wv * 4 + rr;
    size_t grow = (size_t)(m0 + rw) * ND;
    float y0 = Cs[rw][lane] + res[grow + lane];
    float y1 = Cs[rw][lane + 64] + res[grow + lane + 64];
    float s = y0 + y1, ss = y0 * y0 + y1 * y1;
#pragma unroll
    for (int off = 32; off > 0; off >>= 1) {
      s += __shfl_xor(s, off);
      ss += __shfl_xor(ss, off);
    }
    float mean = s * (1.f / ND);
    float var = ss * (1.f / ND) - mean * mean;
    float rstd = rsqrtf(var + 1e-5f);
    xout[grow + lane] = (y0 - mean) * rstd * gamma[lane] + beta[lane];
    xout[grow + lane + 64] =
        (y1 - mean) * rstd * gamma[lane + 64] + beta[lane + 64];
  }
}

// Attention: scores = r.kc (masked) -> softmax -> u = w.kc.  4 elements/block.
// u may alias r (r fully staged to LDS before any u write; element-private).
__global__ __launch_bounds__(256) void attn_k(
    const float* __restrict__ nbf, const float* __restrict__ nbt,
    const float* __restrict__ tf, const float* __restrict__ tp,
    const int* __restrict__ mask, const float* __restrict__ r,
    float* __restrict__ u) {
  __shared__ __align__(16) unsigned short kcb[4][NN][200];  // bf16, padded
  __shared__ __align__(16) float rs[4][768];
  __shared__ __align__(16) float scs[4][NH][NN];
  __shared__ unsigned msks[4];
  const int tid = threadIdx.x;
  const size_t e0 = (size_t)blockIdx.x * 4;

  for (int i = tid; i < 4 * 768 / 4; i += 256)
    *(float4*)&rs[0][i * 4] = *(const float4*)&r[e0 * 768 + i * 4];
  for (int i = tid; i < 4 * NN * (ND / 4); i += 256) {
    int el = i / (NN * 32), rem = i % (NN * 32);
    int n = rem >> 5, cq = rem & 31;
    float4 v = *(const float4*)&nbf[((e0 + el) * NN + n) * ND + cq * 4];
    ushort4 o;
    o.x = f2bf(v.x); o.y = f2bf(v.y); o.z = f2bf(v.z); o.w = f2bf(v.w);
    *(ushort4*)&kcb[el][n][cq * 4] = o;
  }
  for (int i = tid; i < 4 * NN * (TD / 2); i += 256) {
    int el = i / (NN * 32), rem = i % (NN * 32);
    int n = rem >> 5, jp = (rem & 31) * 2;
    float t = nbt[(e0 + el) * NN + n];
    unsigned a = f2bf(__cosf(t * tf[jp] + tp[jp]));
    unsigned b = f2bf(__cosf(t * tf[jp + 1] + tp[jp + 1]));
    *(unsigned*)&kcb[el][n][ND + jp] = a | (b << 16);
  }
  if (tid < 4) {
    unsigned m = 0;
    for (int n = 0; n < NN; ++n)
      m |= (mask[(e0 + tid) * NN + n] != 0 ? 1u : 0u) << n;
    msks[tid] = m;
  }
  __syncthreads();
  for (int idx = tid; idx < 4 * NH * NN; idx += 256) {
    int el = idx / 80, rem = idx % 80;
    int h = rem / 20, n = rem % 20;
    const float* rp = &rs[el][h * 192];
    const unsigned short* kp = &kcb[el][n][0];
    float acc = 0.f;
    for (int c = 0; c < CD; c += 4) {
      float4 rv = *(const float4*)&rp[c];
      ushort4 kv = *(const ushort4*)&kp[c];
      acc += rv.x * bf2f(kv.x) + rv.y * bf2f(kv.y) + rv.z * bf2f(kv.z) +
             rv.w * bf2f(kv.w);
    }
    scs[el][h][n] =
        ((msks[el] >> n) & 1u) ? acc * 0.17677669529663687f : -1e9f;
  }
  __syncthreads();
  if (tid < 4 * NH) {
    int el = tid >> 2, h = tid & 3;
    float mx = -3.4e38f;
#pragma unroll
    for (int n = 0; n < NN; ++n) mx = fmaxf(mx, scs[el][h][n]);
    float ev[NN], s = 0.f;
#pragma unroll
    for (int n = 0; n < NN; ++n) { ev[n] = __expf(scs[el][h][n] - mx); s += ev[n]; }
    float inv = 1.f / s;
#pragma unroll
    for (int n = 0; n < NN; ++n) scs[el][h][n] = ev[n] * inv;
  }
  __syncthreads();
  for (int idx = tid; idx < 4 * NH * (CD / 4); idx += 256) {
    int el = idx / (NH * 48), rem = idx % (NH * 48);
    int h = rem / 48, cq = (rem % 48) * 4;
    float a0 = 0.f, a1 = 0.f, a2 = 0.f, a3 = 0.f;
#pragma unroll
    for (int n = 0; n < NN; ++n) {
      float w = scs[el][h][n];
      ushort4 kv = *(const ushort4*)&kcb[el][n][cq];
      a0 += w * bf2f(kv.x); a1 += w * bf2f(kv.y);
      a2 += w * bf2f(kv.z); a3 += w * bf2f(kv.w);
    }
    *(float4*)&u[(e0 + el) * 768 + h * 192 + cq] = make_float4(a0, a1, a2, a3);
  }
}

__global__ __launch_bounds__(256) void cls_k(
    const float* __restrict__ xf, const float* __restrict__ Wc1,
    const float* __restrict__ bc1, const float* __restrict__ Wc2,
    const float* __restrict__ bc2, float* __restrict__ out) {
  __shared__ float xsh[4][128];
  const int tid = threadIdx.x;
  const size_t e0 = (size_t)blockIdx.x * 4;
  for (int i = tid; i < 512; i += 256) xsh[0][i] = xf[e0 * 128 + i];
  __syncthreads();
  int el = tid >> 6, lane = tid & 63;
  float acc = 0.f;
  for (int c = 0; c < 128; ++c) acc += xsh[el][c] * Wc1[c * 64 + lane];
  acc = fmaxf(acc + bc1[lane], 0.f);
  float p = acc * Wc2[lane];
#pragma unroll
  for (int off = 32; off > 0; off >>= 1) p += __shfl_xor(p, off);
  if (lane == 0) out[e0 + el] = 1.f / (1.f + expf(-(p + bc2[0])));
}

// ---------------------------------------------------------------------------
// Fallback (R5 kernel, G=2/T=256) if workspace is too small for the pipeline.
// ---------------------------------------------------------------------------
#define G 2
#define T 256
#define KCS 196
#define RUS 772

__global__ __launch_bounds__(T, 4) void tgat_fused(
    const float* __restrict__ nf, const float* __restrict__ nbf,
    const float* __restrict__ nt, const float* __restrict__ nbt,
    const float* __restrict__ tf, const float* __restrict__ tp,
    const float* __restrict__ Wq, const float* __restrict__ bq,
    const float* __restrict__ Wk,
    const float* __restrict__ Wv, const float* __restrict__ bv,
    const float* __restrict__ Wo, const float* __restrict__ bo,
    const float* __restrict__ W1, const float* __restrict__ b1,
    const float* __restrict__ W2, const float* __restrict__ b2,
    const float* __restrict__ g1, const float* __restrict__ be1,
    const float* __restrict__ g2, const float* __restrict__ be2,
    const float* __restrict__ Wc1, const float* __restrict__ bc1,
    const float* __restrict__ Wc2, const float* __restrict__ bc2,
    const int* __restrict__ mask,
    float* __restrict__ out) {
  __shared__ __align__(16) unsigned short kc[G][NN][KCS];
  __shared__ __align__(16) float xs[G][ND];
  __shared__ __align__(16) float tqs[G][TD];
  __shared__ __align__(16) float ys[G][HD];
  __shared__ __align__(16) float rus[G][RUS];
  __shared__ __align__(16) float scs[G][NH][NN];
  __shared__ __align__(16) float h1s[G][2 * ND];
  __shared__ __align__(16) unsigned msks[G];
  float* asv = &h1s[0][0];
  const int tid = threadIdx.x;
  const int b0 = blockIdx.x * G;
  {
    int g = tid >> 7, j = tid & 127;
    xs[g][j] = nf[(b0 + g) * ND + j];
  }
  if (tid < G * TD) {
    int g = tid >> 6, j = tid & 63;
    tqs[g][j] = __cosf(nt[b0 + g] * tf[j] + tp[j]);
  }
  if (tid < G) {
    unsigned m = 0;
    for (int n = 0; n < NN; ++n)
      m |= (mask[(b0 + tid) * NN + n] != 0 ? 1u : 0u) << n;
    msks[tid] = m;
  }
  for (int idx = tid; idx < G * NN * (ND / 4); idx += T) {
    int g = idx / (NN * 32), rem = idx % (NN * 32);
    int n = rem >> 5, cq = rem & 31;
    float4 v = *(const float4*)&nbf[(((b0 + g) * NN + n) * ND) + cq * 4];
    ushort4 o;
    o.x = f2bf(v.x); o.y = f2bf(v.y); o.z = f2bf(v.z); o.w = f2bf(v.w);
    *(ushort4*)&kc[g][n][cq * 4] = o;
  }
  for (int idx = tid; idx < G * NN * TD; idx += T) {
    int g = idx / (NN * TD), rem = idx % (NN * TD);
    int n = rem >> 6, j = rem & 63;
    kc[g][n][ND + j] = f2bf(__cosf(nbt[(b0 + g) * NN + n] * tf[j] + tp[j]));
  }
  __syncthreads();
  const float scale = 0.17677669529663687f;
  for (int l = 0; l < NL; ++l) {
    {
      int g = tid >> 7, j = tid & 127;
      const float* wq = Wq + (l * CD) * HD + j;
      float acc = bq[l * HD + j];
      for (int c = 0; c < CD; c += 4) {
        float4 qv = (c < ND) ? *(const float4*)&xs[g][c]
                             : *(const float4*)&tqs[g][c - ND];
        acc += qv.x * wq[(c + 0) * HD] + qv.y * wq[(c + 1) * HD] +
               qv.z * wq[(c + 2) * HD] + qv.w * wq[(c + 3) * HD];
      }
      ys[g][j] = acc;
    }
    __syncthreads();
    for (int rep = 0; rep < 3; ++rep) {
      int i = rep * T + tid;
      int h = i / CD;
      int c2 = i - h * CD;
      const float* wk = Wk + (l * CD + c2) * HD + h * DH;
      const float* yp0 = &ys[0][h * DH];
      const float* yp1 = &ys[1][h * DH];
      float a0 = 0.f, a1 = 0.f;
#pragma unroll
      for (int d = 0; d < DH; d += 4) {
        float4 w4 = *(const float4*)&wk[d];
        float4 y0 = *(const float4*)&yp0[d];
        float4 y1 = *(const float4*)&yp1[d];
        a0 += y0.x * w4.x + y0.y * w4.y + y0.z * w4.z + y0.w * w4.w;
        a1 += y1.x * w4.x + y1.y * w4.y + y1.z * w4.z + y1.w * w4.w;
      }
      rus[0][i] = a0;
      rus[1][i] = a1;
    }
    __syncthreads();
    if (tid < G * NH * NN) {
      int g = tid / (NH * NN), rem = tid % (NH * NN);
      int h = rem / NN, n = rem % NN;
      const float* rp = &rus[g][h * CD];
      const unsigned short* kp = &kc[g][n][0];
      float acc = 0.f;
      for (int c = 0; c < CD; c += 4) {
        float4 rv = *(const float4*)&rp[c];
        ushort4 kv = *(const ushort4*)&kp[c];
        acc += rv.x * bf2f(kv.x) + rv.y * bf2f(kv.y) + rv.z * bf2f(kv.z) +
               rv.w * bf2f(kv.w);
      }
      scs[g][h][n] = ((msks[g] >> n) & 1u) ? acc * scale : -1e9f;
    }
    __syncthreads();
    if (tid < G * NH) {
      int g = tid / NH, h = tid % NH;
      float mx = -3.4e38f;
#pragma unroll
      for (int n = 0; n < NN; ++n) mx = fmaxf(mx, scs[g][h][n]);
      float ev[NN], s = 0.f;
#pragma unroll
      for (int n = 0; n < NN; ++n) { ev[n] = __expf(scs[g][h][n] - mx); s += ev[n]; }
      float inv = 1.f / s;
#pragma unroll
      for (int n = 0; n < NN; ++n) scs[g][h][n] = ev[n] * inv;
    }
    __syncthreads();
    for (int flat = tid; flat < G * NH * (CD / 4); flat += T) {
      int g = flat / (NH * 48), iq = flat % (NH * 48);
      int h = iq / 48, c = (iq % 48) * 4;
      const unsigned short* kp = &kc[g][0][0];
      float a0 = 0.f, a1 = 0.f, a2 = 0.f, a3 = 0.f;
#pragma unroll
      for (int n = 0; n < NN; ++n) {
        float w = scs[g][h][n];
        ushort4 kv = *(const ushort4*)&kp[n * KCS + c];
        a0 += w * bf2f(kv.x); a1 += w * bf2f(kv.y);
        a2 += w * bf2f(kv.z); a3 += w * bf2f(kv.w);
      }
      *(float4*)&rus[g][h * CD + c] = make_float4(a0, a1, a2, a3);
    }
    __syncthreads();
    {
      int j = tid & (HD - 1);
      int g = tid >> 7;
      int h = j >> 5;
      const float* wv = Wv + (l * CD) * HD + j;
      float acc = 0.f;
      for (int c = 0; c < CD; c += 4) {
        float4 uv = *(const float4*)&rus[g][h * CD + c];
        acc += uv.x * wv[(c + 0) * HD] + uv.y * wv[(c + 1) * HD] +
               uv.z * wv[(c + 2) * HD] + uv.w * wv[(c + 3) * HD];
      }
      asv[g * HD + j] = acc + bv[l * HD + j];
    }
    __syncthreads();
    {
      int j = tid & (ND - 1);
      int g = tid >> 7;
      const float* wo = Wo + (l * HD) * ND + j;
      float acc = 0.f;
      for (int c = 0; c < HD; c += 4) {
        float4 av = *(const float4*)&asv[g * HD + c];
        acc += av.x * wo[(c + 0) * ND] + av.y * wo[(c + 1) * ND] +
               av.z * wo[(c + 2) * ND] + av.w * wo[(c + 3) * ND];
      }
      rus[g][j] = acc + bo[l * ND + j];
    }
    __syncthreads();
    if (tid < G * 64) {
      int g = tid >> 6, lane = tid & 63;
      float y0 = xs[g][lane] + rus[g][lane];
      float y1 = xs[g][lane + 64] + rus[g][lane + 64];
      float s = y0 + y1, ss = y0 * y0 + y1 * y1;
#pragma unroll
      for (int off = 32; off > 0; off >>= 1) {
        s += __shfl_xor(s, off);
        ss += __shfl_xor(ss, off);
      }
      float mean = s * (1.f / ND);
      float var = ss * (1.f / ND) - mean * mean;
      float rstd = rsqrtf(var + 1e-5f);
      xs[g][lane] = (y0 - mean) * rstd * g1[l * ND + lane] + be1[l * ND + lane];
      xs[g][lane + 64] =
          (y1 - mean) * rstd * g1[l * ND + lane + 64] + be1[l * ND + lane + 64];
    }
    __syncthreads();
    {
      int j = tid;
      const float* w1p = W1 + (l * ND) * (2 * ND) + j;
      float acc0 = 0.f, acc1 = 0.f;
      for (int c = 0; c < ND; c += 4) {
        float w0 = w1p[(c + 0) * 2 * ND], wa = w1p[(c + 1) * 2 * ND],
              w2 = w1p[(c + 2) * 2 * ND], w3 = w1p[(c + 3) * 2 * ND];
        float4 x0 = *(const float4*)&xs[0][c];
        float4 x1 = *(const float4*)&xs[1][c];
        acc0 += x0.x * w0 + x0.y * wa + x0.z * w2 + x0.w * w3;
        acc1 += x1.x * w0 + x1.y * wa + x1.z * w2 + x1.w * w3;
      }
      float b1v = b1[l * 2 * ND + j];
      h1s[0][j] = fmaxf(acc0 + b1v, 0.f);
      h1s[1][j] = fmaxf(acc1 + b1v, 0.f);
    }
    __syncthreads();
    {
      int j = tid & (ND - 1);
      int g = tid >> 7;
      const float* w2p = W2 + (l * 2 * ND) * ND + j;
      float acc = 0.f;
      for (int c = 0; c < 2 * ND; c += 4) {
        float4 hv = *(const float4*)&h1s[g][c];
        acc += hv.x * w2p[(c + 0) * ND] + hv.y * w2p[(c + 1) * ND] +
               hv.z * w2p[(c + 2) * ND] + hv.w * w2p[(c + 3) * ND];
      }
      rus[g][j] = acc + b2[l * ND + j];
    }
    __syncthreads();
    if (tid < G * 64) {
      int g = tid >> 6, lane = tid & 63;
      float y0 = xs[g][lane] + rus[g][lane];
      float y1 = xs[g][lane + 64] + rus[g][lane + 64];
      float s = y0 + y1, ss = y0 * y0 + y1 * y1;
#pragma unroll
      for (int off = 32; off > 0; off >>= 1) {
        s += __shfl_xor(s, off);
        ss += __shfl_xor(ss, off);
      }
      float mean = s * (1.f / ND);
      float var = ss * (1.f / ND) - mean * mean;
      float rstd = rsqrtf(var + 1e-5f);
      xs[g][lane] = (y0 - mean) * rstd * g2[l * ND + lane] + be2[l * ND + lane];
      xs[g][lane + 64] =
          (y1 - mean) * rstd * g2[l * ND + lane + 64] + be2[l * ND + lane + 64];
    }
    __syncthreads();
  }
  if (tid < G * 64) {
    int j = tid & 63;
    int g = tid >> 6;
    const float* wc = Wc1 + j;
    float acc = 0.f;
    for (int c = 0; c < ND; c += 4) {
      float4 xv = *(const float4*)&xs[g][c];
      acc += xv.x * wc[(c + 0) * 64] + xv.y * wc[(c + 1) * 64] +
             xv.z * wc[(c + 2) * 64] + xv.w * wc[(c + 3) * 64];
    }
    ((float*)scs)[g * 64 + j] = fmaxf(acc + bc1[j], 0.f);
  }
  __syncthreads();
  if (tid < G * 64) {
    int g = tid >> 6, lane = tid & 63;
    float p = ((float*)scs)[g * 64 + lane] * Wc2[lane];
#pragma unroll
    for (int off = 32; off > 0; off >>= 1) p += __shfl_xor(p, off);
    if (lane == 0) {
      float z = p + bc2[0];
      out[b0 + g] = 1.f / (1.f + expf(-z));
    }
  }
}

extern "C" void kernel_launch(void* const* d_in, const int* in_sizes, int n_in,
                              void* d_out, int out_size, void* d_ws,
                              size_t ws_size, hipStream_t stream) {
  (void)in_sizes; (void)n_in; (void)out_size;
  const float* nf  = (const float*)d_in[0];
  const float* nbf = (const float*)d_in[1];
  const float* ntm = (const float*)d_in[2];
  const float* nbt = (const float*)d_in[3];
  const float* tf  = (const float*)d_in[4];
  const float* tp  = (const float*)d_in[5];
  const float* Wq  = (const float*)d_in[6];
  const float* bq  = (const float*)d_in[7];
  const float* Wk  = (const float*)d_in[8];
  // d_in[9] = bk: n-uniform score shift -> softmax-invariant -> dropped
  const float* Wv  = (const float*)d_in[10];
  const float* bv  = (const float*)d_in[11];
  const float* Wo  = (const float*)d_in[12];
  const float* bo  = (const float*)d_in[13];
  const float* W1  = (const float*)d_in[14];
  const float* b1  = (const float*)d_in[15];
  const float* W2  = (const float*)d_in[16];
  const float* b2  = (const float*)d_in[17];
  const float* g1  = (const float*)d_in[18];
  const float* be1 = (const float*)d_in[19];
  const float* g2  = (const float*)d_in[20];
  const float* be2 = (const float*)d_in[21];
  const float* Wc1 = (const float*)d_in[22];
  const float* bc1 = (const float*)d_in[23];
  const float* Wc2 = (const float*)d_in[24];
  const float* bc2 = (const float*)d_in[25];
  const int* mask  = (const int*)d_in[26];
  float* out = (float*)d_out;

  const size_t NEED = 589422592ull;  // WF 622,592 + f32 intermediates
  if (ws_size >= NEED) {
    unsigned short* WF = (unsigned short*)d_ws;
    float* tqf = (float*)((char*)d_ws + 622592);
    float* yb  = tqf + 6400000;    // [100K x 128]
    float* rb  = yb + 12800000;    // [100K x 768]  (u aliases r)
    float* ab  = rb + 76800000;    // [100K x 128]
    float* h1b = ab + 12800000;    // [100K x 256]
    float* xfb = h1b + 25600000;   // [100K x 128]

    conv_w<<<608, 256, 0, stream>>>(Wq, Wk, Wv, Wo, W1, W2, WF);
    prep_tq<<<25000, 256, 0, stream>>>(ntm, tf, tp, tqf);
    const float* xsrc = nf;
    for (int l = 0; l < NL; ++l) {
      const unsigned short* WFl = WF + (size_t)l * 155648;
      // y = [x|tq] @ Wq + bq
      gemm16<2><<<dim3(6250, 1), 256, 0, stream>>>(
          xsrc, ND, tqf, TD, 128, WFl, 6, 8, 0, 0, 0, bq + l * HD, yb, HD, 0);
      // r_h = y_h @ Wk_h^T
      gemm16<3><<<dim3(6250, 4), 256, 0, stream>>>(
          yb, HD, nullptr, 0, 1 << 30, WFl + 24576, 1, 12, DH, 192, 12,
          nullptr, rb, 768, 0);
      // scores/softmax/u (u overwrites r)
      attn_k<<<25000, 256, 0, stream>>>(nbf, nbt, tf, tp, mask, rb, rb);
      // a_h = u_h @ Wv_h + bv
      gemm16<1><<<dim3(6250, 4), 128, 0, stream>>>(
          rb, 768, nullptr, 0, 1 << 30, WFl + 49152, 6, 2, 192, DH, 12,
          bv + l * HD, ab, HD, 0);
      // x = LN1(x + a @ Wo + bo)
      gemm_ln<<<6250, 256, 0, stream>>>(ab, HD, 4, WFl + 73728, bo + l * ND,
                                        xsrc, g1 + l * ND, be1 + l * ND, xfb);
      // h1 = relu(x @ W1 + b1)
      gemm16<4><<<dim3(6250, 1), 256, 0, stream>>>(
          xfb, ND, nullptr, 0, 1 << 30, WFl + 90112, 4, 16, 0, 0, 0,
          b1 + l * 2 * ND, h1b, 2 * ND, 1);
      // x = LN2(x + h1 @ W2 + b2)
      gemm_ln<<<6250, 256, 0, stream>>>(h1b, 2 * ND, 8, WFl + 122880,
                                        b2 + l * ND, xfb, g2 + l * ND,
                                        be2 + l * ND, xfb);
      xsrc = xfb;
    }
    cls_k<<<25000, 256, 0, stream>>>(xfb, Wc1, bc1, Wc2, bc2, out);
  } else {
    tgat_fused<<<BB / G, T, 0, stream>>>(nf, nbf, ntm, nbt, tf, tp, Wq, bq, Wk,
                                         Wv, bv, Wo, bo, W1, b1, W2, b2, g1,
                                         be1, g2, be2, Wc1, bc1, Wc2, bc2,
                                         mask, out);
  }
}

// Round 7
// 1704.329 us; speedup vs baseline: 3.0953x; 1.3255x over previous
//
#include <hip/hip_runtime.h>

#define BB 100000
#define NN 20
#define ND 128
#define TD 64
#define CD 192
#define HD 128
#define NH 4
#define DH 32
#define NL 2

typedef __attribute__((ext_vector_type(8))) short bf16x8;
typedef __attribute__((ext_vector_type(4))) float f32x4;

static __device__ __forceinline__ float bf2f(unsigned short u) {
  return __uint_as_float(((unsigned)u) << 16);
}
static __device__ __forceinline__ unsigned short f2bf(float x) {
  unsigned b = __float_as_uint(x);
  return (unsigned short)((b + 0x7FFFu + ((b >> 16) & 1u)) >> 16);
}
static __device__ __forceinline__ bf16x8 load_a8(const float* p) {
  float4 a = *(const float4*)p, b = *(const float4*)(p + 4);
  bf16x8 r;
  r[0] = (short)f2bf(a.x); r[1] = (short)f2bf(a.y);
  r[2] = (short)f2bf(a.z); r[3] = (short)f2bf(a.w);
  r[4] = (short)f2bf(b.x); r[5] = (short)f2bf(b.y);
  r[6] = (short)f2bf(b.z); r[7] = (short)f2bf(b.w);
  return r;
}

// ---------------------------------------------------------------------------
// MFMA pipeline (16x16x32 bf16). Fragment layouts as R6 (HW-verified m89).
// Per-layer WF layout (u16 units, 512/tile): tiles 0-47 Wq[kt*8+nt],
// 48-95 Wk^T[h*12+nt], 96-143 Wv[h*12+kt*2+nt], 144-175 Wo[kt*8+nt],
// 176-239 W1[kt*16+nt], 240-303 W2[kt*8+nt].  Layer stride 155,648 u16.
// R7: attn blocks 2-el (LDS 46->23KB, occupancy lever); tier-A precomputed
// bf16 kc (no per-layer cos/f2bf); y/ab/h1 stored bf16 (f2bf moved from
// consumer load to producer store -> bit-identical, half the traffic).
// ---------------------------------------------------------------------------

__global__ __launch_bounds__(256) void conv_w(
    const float* __restrict__ Wq, const float* __restrict__ Wk,
    const float* __restrict__ Wv, const float* __restrict__ Wo,
    const float* __restrict__ W1, const float* __restrict__ W2,
    unsigned short* __restrict__ WF) {
  int t = blockIdx.x;
  int l = t / 304, tt = t % 304;
#pragma unroll
  for (int e = 0; e < 2; ++e) {
    int idx = threadIdx.x * 2 + e;      // 0..511 element within tile
    int lane = idx >> 3, j = idx & 7;
    int wk = ((lane >> 4) << 3) + j;    // within-tile k 0..31
    int c16 = lane & 15;
    float v;
    if (tt < 48) {                      // Wq [192x128]
      int kt = tt >> 3, n2 = tt & 7;
      v = Wq[((size_t)l * CD + kt * 32 + wk) * HD + n2 * 16 + c16];
    } else if (tt < 96) {               // Wk^T per head [32x192]
      int t2 = tt - 48; int h = t2 / 12, n2 = t2 % 12;
      v = Wk[((size_t)l * CD + n2 * 16 + c16) * HD + h * 32 + wk];
    } else if (tt < 144) {              // Wv per head [192x32]
      int t2 = tt - 96; int h = t2 / 12, r2 = t2 % 12, kt = r2 >> 1, n2 = r2 & 1;
      v = Wv[((size_t)l * CD + kt * 32 + wk) * HD + h * 32 + n2 * 16 + c16];
    } else if (tt < 176) {              // Wo [128x128]
      int t2 = tt - 144; int kt = t2 >> 3, n2 = t2 & 7;
      v = Wo[((size_t)l * HD + kt * 32 + wk) * ND + n2 * 16 + c16];
    } else if (tt < 240) {              // W1 [128x256]
      int t2 = tt - 176; int kt = t2 >> 4, n2 = t2 & 15;
      v = W1[((size_t)l * ND + kt * 32 + wk) * (2 * ND) + n2 * 16 + c16];
    } else {                            // W2 [256x128]
      int t2 = tt - 240; int kt = t2 >> 3, n2 = t2 & 7;
      v = W2[((size_t)l * 2 * ND + kt * 32 + wk) * ND + n2 * 16 + c16];
    }
    WF[(size_t)l * 155648 + (size_t)tt * 512 + idx] = f2bf(v);
  }
}

__global__ __launch_bounds__(256) void prep_tq(
    const float* __restrict__ ntime, const float* __restrict__ tf,
    const float* __restrict__ tp, float* __restrict__ tqf) {
  int i = blockIdx.x * 256 + threadIdx.x;  // 0..6.4M
  int b = i >> 6, j = i & 63;
  tqf[i] = __cosf(ntime[b] * tf[j] + tp[j]);
}

// kcf[e][n][c] bf16: c<128 from nbf (f2bf), c>=128 cos time encoding.
// 48M units of 8 c each.
__global__ __launch_bounds__(256) void prep_kc(
    const float* __restrict__ nbf, const float* __restrict__ nbt,
    const float* __restrict__ tf, const float* __restrict__ tp,
    unsigned short* __restrict__ kcf) {
  long long i = (long long)blockIdx.x * 256 + threadIdx.x;
  int q = (int)(i % 24);
  long long en = i / 24;  // e*20+n
  unsigned short o[8];
  if (q < 16) {
    const float* p = nbf + en * 128 + q * 8;
    float4 a = *(const float4*)p, b = *(const float4*)(p + 4);
    o[0] = f2bf(a.x); o[1] = f2bf(a.y); o[2] = f2bf(a.z); o[3] = f2bf(a.w);
    o[4] = f2bf(b.x); o[5] = f2bf(b.y); o[6] = f2bf(b.z); o[7] = f2bf(b.w);
  } else {
    float t = nbt[en];
    int j0 = (q - 16) * 8;
#pragma unroll
    for (int k = 0; k < 8; ++k) o[k] = f2bf(__cosf(t * tf[j0 + k] + tp[j0 + k]));
  }
  uint4 w;
  w.x = (unsigned)o[0] | ((unsigned)o[1] << 16);
  w.y = (unsigned)o[2] | ((unsigned)o[3] << 16);
  w.z = (unsigned)o[4] | ((unsigned)o[5] << 16);
  w.w = (unsigned)o[6] | ((unsigned)o[7] << 16);
  *(uint4*)&kcf[en * 192 + q * 8] = w;
}

__global__ __launch_bounds__(256) void prep_mb(const int* __restrict__ mask,
                                               unsigned* __restrict__ mb) {
  int e = blockIdx.x * 256 + threadIdx.x;
  if (e < BB) {
    unsigned m = 0;
    for (int n = 0; n < NN; ++n)
      m |= (mask[(size_t)e * NN + n] != 0 ? 1u : 0u) << n;
    mb[e] = m;
  }
}

// Generic 16-row-block GEMM. ABF: A is bf16; OBF: output bf16 (f2bf at store
// == f2bf at consumer load -> bit-identical). A2 concat source always f32.
template <int TN, int ABF, int OBF>
__global__ __launch_bounds__(256) void gemm16(
    const void* __restrict__ A, int lda,
    const float* __restrict__ A2, int lda2, int ksplit,
    const unsigned short* __restrict__ BF,
    int ktiles, int ntiles, int aKoffMul, int cColMul, int segBMul,
    const float* __restrict__ bias,
    void* __restrict__ C, int ldc, int relu) {
  const int tid = threadIdx.x;
  const int wv = tid >> 6, lane = tid & 63;
  const int NW = blockDim.x >> 6;
  const int m0 = blockIdx.x << 4;
  const int seg = blockIdx.y;
  const int arow = m0 + (lane & 15);
  const int kgrp = (lane >> 4) << 3;
  const int aK = seg * aKoffMul;
  const unsigned short* Bseg = BF + (size_t)seg * segBMul * 512;
  f32x4 acc[TN];
#pragma unroll
  for (int i = 0; i < TN; ++i) acc[i] = f32x4{0.f, 0.f, 0.f, 0.f};
  for (int kt = 0; kt < ktiles; ++kt) {
    bf16x8 af;
    if (kt * 32 >= ksplit) {
      af = load_a8(A2 + (size_t)arow * lda2 + (kt * 32 - ksplit) + kgrp);
    } else if (ABF) {
      af = *(const bf16x8*)((const unsigned short*)A + (size_t)arow * lda + aK +
                            kt * 32 + kgrp);
    } else {
      af = load_a8((const float*)A + (size_t)arow * lda + aK + kt * 32 + kgrp);
    }
#pragma unroll
    for (int i = 0; i < TN; ++i) {
      int nt = wv + NW * i;
      bf16x8 bf = *(const bf16x8*)(Bseg + (((size_t)(kt * ntiles + nt)) << 9) +
                                   (lane << 3));
      acc[i] = __builtin_amdgcn_mfma_f32_16x16x32_bf16(af, bf, acc[i], 0, 0, 0);
    }
  }
  const int crow = m0 + ((lane >> 4) << 2);
#pragma unroll
  for (int i = 0; i < TN; ++i) {
    int nt = wv + NW * i;
    int col = seg * cColMul + nt * 16 + (lane & 15);
    float bv = bias ? bias[col] : 0.f;
#pragma unroll
    for (int rr = 0; rr < 4; ++rr) {
      float v = acc[i][rr] + bv;
      if (relu) v = fmaxf(v, 0.f);
      if (OBF)
        ((unsigned short*)C)[(size_t)(crow + rr) * ldc + col] = f2bf(v);
      else
        ((float*)C)[(size_t)(crow + rr) * ldc + col] = v;
    }
  }
}

// GEMM (N=128) + bias + residual + LayerNorm fused epilogue -> xout f32.
// In-place res==xout safe (thread reads exactly what it writes).
template <int ABF>
__global__ __launch_bounds__(256) void gemm_ln(
    const void* __restrict__ A, int lda, int ktiles,
    const unsigned short* __restrict__ BF,
    const float* __restrict__ bias, const float* __restrict__ res,
    const float* __restrict__ gamma, const float* __restrict__ beta,
    float* __restrict__ xout) {
  __shared__ float Cs[16][132];
  const int tid = threadIdx.x;
  const int wv = tid >> 6, lane = tid & 63;
  const int m0 = blockIdx.x << 4;
  const int arow = m0 + (lane & 15);
  const int kgrp = (lane >> 4) << 3;
  const int nt0 = wv, nt1 = wv + 4;
  f32x4 acc0 = {0.f, 0.f, 0.f, 0.f}, acc1 = {0.f, 0.f, 0.f, 0.f};
  for (int kt = 0; kt < ktiles; ++kt) {
    bf16x8 af;
    if (ABF)
      af = *(const bf16x8*)((const unsigned short*)A + (size_t)arow * lda +
                            kt * 32 + kgrp);
    else
      af = load_a8((const float*)A + (size_t)arow * lda + kt * 32 + kgrp);
    bf16x8 b0 = *(const bf16x8*)(BF + (((size_t)(kt * 8 + nt0)) << 9) + (lane << 3));
    bf16x8 b1 = *(const bf16x8*)(BF + (((size_t)(kt * 8 + nt1)) << 9) + (lane << 3));
    acc0 = __builtin_amdgcn_mfma_f32_16x16x32_bf16(af, b0, acc0, 0, 0, 0);
    acc1 = __builtin_amdgcn_mfma_f32_16x16x32_bf16(af, b1, acc1, 0, 0, 0);
  }
  {
    const int lrow = (lane >> 4) << 2;
    int c0 = nt0 * 16 + (lane & 15), c1 = nt1 * 16 + (lane & 15);
    float bv0 = bias[c0], bv1 = bias[c1];
#pragma unroll
    for (int rr = 0; rr < 4; ++rr) {
      Cs[lrow + rr][c0] = acc0[rr] + bv0;
      Cs[lrow + rr][c1] = acc1[rr] + bv1;
    }
  }
  __syncthreads();
#pragma unroll
  for (int rr = 0; rr < 4; ++rr) {
    int rw = wv * 4 + rr;
    size_t grow = (size_t)(m0 + rw) * ND;
    float y0 = Cs[rw][lane] + res[grow + lane];
    float y1 = Cs[rw][lane + 64] + res[grow + lane + 64];
    float s = y0 + y1, ss = y0 * y0 + y1 * y1;
#pragma unroll
    for (int off = 32; off > 0; off >>= 1) {
      s += __shfl_xor(s, off);
      ss += __shfl_xor(ss, off);
    }
    float mean = s * (1.f / ND);
    float var = ss * (1.f / ND) - mean * mean;
    float rstd = rsqrtf(var + 1e-5f);
    xout[grow + lane] = (y0 - mean) * rstd * gamma[lane] + beta[lane];
    xout[grow + lane + 64] =
        (y1 - mean) * rstd * gamma[lane + 64] + beta[lane + 64];
  }
}

// Attention, 2 elements/block (~23KB LDS -> up to 6-7 blocks/CU).
// Tier A: kc read from precomputed bf16 kcf (no cos/f2bf staging VALU).
// u (f32) aliases r: element-private, r staged to LDS before u writes.
__global__ __launch_bounds__(256) void attn_k2(
    const unsigned short* __restrict__ kcf, const unsigned* __restrict__ mb,
    const float* __restrict__ r, float* __restrict__ u) {
  __shared__ __align__(16) unsigned short kcb[2][NN][200];
  __shared__ __align__(16) float rs[2][768];
  __shared__ __align__(16) float scs[2][NH][NN];
  __shared__ unsigned msks[2];
  const int tid = threadIdx.x;
  const size_t e0 = (size_t)blockIdx.x * 2;
  {
    ((float4*)rs)[tid] = ((const float4*)r)[e0 * 192 + tid];
    if (tid < 128)
      ((float4*)rs)[tid + 256] = ((const float4*)r)[e0 * 192 + tid + 256];
  }
  for (int i = tid; i < 960; i += 256) {  // 16B chunks of kc
    int el = i / 480, rem = i % 480;
    int n = rem / 24, q = rem % 24;
    *(uint4*)&kcb[el][n][q * 8] =
        *(const uint4*)&kcf[((e0 + el) * NN + n) * 192 + q * 8];
  }
  if (tid < 2) msks[tid] = mb[e0 + tid];
  __syncthreads();
  if (tid < 2 * NH * NN) {
    int el = tid / (NH * NN), rem = tid % (NH * NN);
    int h = rem / NN, n = rem % NN;
    const float* rp = &rs[el][h * CD];
    const unsigned short* kp = &kcb[el][n][0];
    float acc = 0.f;
    for (int c = 0; c < CD; c += 4) {
      float4 rv = *(const float4*)&rp[c];
      ushort4 kv = *(const ushort4*)&kp[c];
      acc += rv.x * bf2f(kv.x) + rv.y * bf2f(kv.y) + rv.z * bf2f(kv.z) +
             rv.w * bf2f(kv.w);
    }
    scs[el][h][n] =
        ((msks[el] >> n) & 1u) ? acc * 0.17677669529663687f : -1e9f;
  }
  __syncthreads();
  if (tid < 2 * NH) {
    int el = tid >> 2, h = tid & 3;
    float mx = -3.4e38f;
#pragma unroll
    for (int n = 0; n < NN; ++n) mx = fmaxf(mx, scs[el][h][n]);
    float ev[NN], s = 0.f;
#pragma unroll
    for (int n = 0; n < NN; ++n) { ev[n] = __expf(scs[el][h][n] - mx); s += ev[n]; }
    float inv = 1.f / s;
#pragma unroll
    for (int n = 0; n < NN; ++n) scs[el][h][n] = ev[n] * inv;
  }
  __syncthreads();
  for (int i = tid; i < 2 * NH * (CD / 4); i += 256) {  // 384 quads
    int el = i / (NH * 48), rem = i % (NH * 48);
    int h = rem / 48, cq = (rem % 48) * 4;
    float a0 = 0.f, a1 = 0.f, a2 = 0.f, a3 = 0.f;
#pragma unroll
    for (int n = 0; n < NN; ++n) {
      float w = scs[el][h][n];
      ushort4 kv = *(const ushort4*)&kcb[el][n][cq];
      a0 += w * bf2f(kv.x); a1 += w * bf2f(kv.y);
      a2 += w * bf2f(kv.z); a3 += w * bf2f(kv.w);
    }
    *(float4*)&u[(e0 + el) * 768 + h * 192 + cq] = make_float4(a0, a1, a2, a3);
  }
}

// Tier B: same 2-el structure, kc computed in-kernel (cos + f2bf).
__global__ __launch_bounds__(256) void attn_kb(
    const float* __restrict__ nbf, const float* __restrict__ nbt,
    const float* __restrict__ tf, const float* __restrict__ tp,
    const unsigned* __restrict__ mb, const float* __restrict__ r,
    float* __restrict__ u) {
  __shared__ __align__(16) unsigned short kcb[2][NN][200];
  __shared__ __align__(16) float rs[2][768];
  __shared__ __align__(16) float scs[2][NH][NN];
  __shared__ unsigned msks[2];
  const int tid = threadIdx.x;
  const size_t e0 = (size_t)blockIdx.x * 2;
  {
    ((float4*)rs)[tid] = ((const float4*)r)[e0 * 192 + tid];
    if (tid < 128)
      ((float4*)rs)[tid + 256] = ((const float4*)r)[e0 * 192 + tid + 256];
  }
  for (int i = tid; i < 2 * NN * 32; i += 256) {
    int el = i / (NN * 32), rem = i % (NN * 32);
    int n = rem >> 5, cq = rem & 31;
    float4 v = *(const float4*)&nbf[((e0 + el) * NN + n) * ND + cq * 4];
    ushort4 o;
    o.x = f2bf(v.x); o.y = f2bf(v.y); o.z = f2bf(v.z); o.w = f2bf(v.w);
    *(ushort4*)&kcb[el][n][cq * 4] = o;
  }
  for (int i = tid; i < 2 * NN * 32; i += 256) {
    int el = i / (NN * 32), rem = i % (NN * 32);
    int n = rem >> 5, jp = (rem & 31) * 2;
    float t = nbt[(e0 + el) * NN + n];
    unsigned a = f2bf(__cosf(t * tf[jp] + tp[jp]));
    unsigned b = f2bf(__cosf(t * tf[jp + 1] + tp[jp + 1]));
    *(unsigned*)&kcb[el][n][ND + jp] = a | (b << 16);
  }
  if (tid < 2) msks[tid] = mb[e0 + tid];
  __syncthreads();
  if (tid < 2 * NH * NN) {
    int el = tid / (NH * NN), rem = tid % (NH * NN);
    int h = rem / NN, n = rem % NN;
    const float* rp = &rs[el][h * CD];
    const unsigned short* kp = &kcb[el][n][0];
    float acc = 0.f;
    for (int c = 0; c < CD; c += 4) {
      float4 rv = *(const float4*)&rp[c];
      ushort4 kv = *(const ushort4*)&kp[c];
      acc += rv.x * bf2f(kv.x) + rv.y * bf2f(kv.y) + rv.z * bf2f(kv.z) +
             rv.w * bf2f(kv.w);
    }
    scs[el][h][n] =
        ((msks[el] >> n) & 1u) ? acc * 0.17677669529663687f : -1e9f;
  }
  __syncthreads();
  if (tid < 2 * NH) {
    int el = tid >> 2, h = tid & 3;
    float mx = -3.4e38f;
#pragma unroll
    for (int n = 0; n < NN; ++n) mx = fmaxf(mx, scs[el][h][n]);
    float ev[NN], s = 0.f;
#pragma unroll
    for (int n = 0; n < NN; ++n) { ev[n] = __expf(scs[el][h][n] - mx); s += ev[n]; }
    float inv = 1.f / s;
#pragma unroll
    for (int n = 0; n < NN; ++n) scs[el][h][n] = ev[n] * inv;
  }
  __syncthreads();
  for (int i = tid; i < 2 * NH * (CD / 4); i += 256) {
    int el = i / (NH * 48), rem = i % (NH * 48);
    int h = rem / 48, cq = (rem % 48) * 4;
    float a0 = 0.f, a1 = 0.f, a2 = 0.f, a3 = 0.f;
#pragma unroll
    for (int n = 0; n < NN; ++n) {
      float w = scs[el][h][n];
      ushort4 kv = *(const ushort4*)&kcb[el][n][cq];
      a0 += w * bf2f(kv.x); a1 += w * bf2f(kv.y);
      a2 += w * bf2f(kv.z); a3 += w * bf2f(kv.w);
    }
    *(float4*)&u[(e0 + el) * 768 + h * 192 + cq] = make_float4(a0, a1, a2, a3);
  }
}

__global__ __launch_bounds__(256) void cls_k(
    const float* __restrict__ xf, const float* __restrict__ Wc1,
    const float* __restrict__ bc1, const float* __restrict__ Wc2,
    const float* __restrict__ bc2, float* __restrict__ out) {
  __shared__ float xsh[4][128];
  const int tid = threadIdx.x;
  const size_t e0 = (size_t)blockIdx.x * 4;
  for (int i = tid; i < 512; i += 256) xsh[0][i] = xf[e0 * 128 + i];
  __syncthreads();
  int el = tid >> 6, lane = tid & 63;
  float acc = 0.f;
  for (int c = 0; c < 128; ++c) acc += xsh[el][c] * Wc1[c * 64 + lane];
  acc = fmaxf(acc + bc1[lane], 0.f);
  float p = acc * Wc2[lane];
#pragma unroll
  for (int off = 32; off > 0; off >>= 1) p += __shfl_xor(p, off);
  if (lane == 0) out[e0 + el] = 1.f / (1.f + expf(-(p + bc2[0])));
}

// ---------------------------------------------------------------------------
// Tier C fallback (R5 fused kernel) if workspace is tiny.
// ---------------------------------------------------------------------------
#define G 2
#define T 256
#define KCS 196
#define RUS 772

__global__ __launch_bounds__(T, 4) void tgat_fused(
    const float* __restrict__ nf, const float* __restrict__ nbf,
    const float* __restrict__ nt, const float* __restrict__ nbt,
    const float* __restrict__ tf, const float* __restrict__ tp,
    const float* __restrict__ Wq, const float* __restrict__ bq,
    const float* __restrict__ Wk,
    const float* __restrict__ Wv, const float* __restrict__ bv,
    const float* __restrict__ Wo, const float* __restrict__ bo,
    const float* __restrict__ W1, const float* __restrict__ b1,
    const float* __restrict__ W2, const float* __restrict__ b2,
    const float* __restrict__ g1, const float* __restrict__ be1,
    const float* __restrict__ g2, const float* __restrict__ be2,
    const float* __restrict__ Wc1, const float* __restrict__ bc1,
    const float* __restrict__ Wc2, const float* __restrict__ bc2,
    const int* __restrict__ mask,
    float* __restrict__ out) {
  __shared__ __align__(16) unsigned short kc[G][NN][KCS];
  __shared__ __align__(16) float xs[G][ND];
  __shared__ __align__(16) float tqs[G][TD];
  __shared__ __align__(16) float ys[G][HD];
  __shared__ __align__(16) float rus[G][RUS];
  __shared__ __align__(16) float scs[G][NH][NN];
  __shared__ __align__(16) float h1s[G][2 * ND];
  __shared__ __align__(16) unsigned msks[G];
  float* asv = &h1s[0][0];
  const int tid = threadIdx.x;
  const int b0 = blockIdx.x * G;
  {
    int g = tid >> 7, j = tid & 127;
    xs[g][j] = nf[(b0 + g) * ND + j];
  }
  if (tid < G * TD) {
    int g = tid >> 6, j = tid & 63;
    tqs[g][j] = __cosf(nt[b0 + g] * tf[j] + tp[j]);
  }
  if (tid < G) {
    unsigned m = 0;
    for (int n = 0; n < NN; ++n)
      m |= (mask[(b0 + tid) * NN + n] != 0 ? 1u : 0u) << n;
    msks[tid] = m;
  }
  for (int idx = tid; idx < G * NN * (ND / 4); idx += T) {
    int g = idx / (NN * 32), rem = idx % (NN * 32);
    int n = rem >> 5, cq = rem & 31;
    float4 v = *(const float4*)&nbf[(((b0 + g) * NN + n) * ND) + cq * 4];
    ushort4 o;
    o.x = f2bf(v.x); o.y = f2bf(v.y); o.z = f2bf(v.z); o.w = f2bf(v.w);
    *(ushort4*)&kc[g][n][cq * 4] = o;
  }
  for (int idx = tid; idx < G * NN * TD; idx += T) {
    int g = idx / (NN * TD), rem = idx % (NN * TD);
    int n = rem >> 6, j = rem & 63;
    kc[g][n][ND + j] = f2bf(__cosf(nbt[(b0 + g) * NN + n] * tf[j] + tp[j]));
  }
  __syncthreads();
  const float scale = 0.17677669529663687f;
  for (int l = 0; l < NL; ++l) {
    {
      int g = tid >> 7, j = tid & 127;
      const float* wq = Wq + (l * CD) * HD + j;
      float acc = bq[l * HD + j];
      for (int c = 0; c < CD; c += 4) {
        float4 qv = (c < ND) ? *(const float4*)&xs[g][c]
                             : *(const float4*)&tqs[g][c - ND];
        acc += qv.x * wq[(c + 0) * HD] + qv.y * wq[(c + 1) * HD] +
               qv.z * wq[(c + 2) * HD] + qv.w * wq[(c + 3) * HD];
      }
      ys[g][j] = acc;
    }
    __syncthreads();
    for (int rep = 0; rep < 3; ++rep) {
      int i = rep * T + tid;
      int h = i / CD;
      int c2 = i - h * CD;
      const float* wk = Wk + (l * CD + c2) * HD + h * DH;
      const float* yp0 = &ys[0][h * DH];
      const float* yp1 = &ys[1][h * DH];
      float a0 = 0.f, a1 = 0.f;
#pragma unroll
      for (int d = 0; d < DH; d += 4) {
        float4 w4 = *(const float4*)&wk[d];
        float4 y0 = *(const float4*)&yp0[d];
        float4 y1 = *(const float4*)&yp1[d];
        a0 += y0.x * w4.x + y0.y * w4.y + y0.z * w4.z + y0.w * w4.w;
        a1 += y1.x * w4.x + y1.y * w4.y + y1.z * w4.z + y1.w * w4.w;
      }
      rus[0][i] = a0;
      rus[1][i] = a1;
    }
    __syncthreads();
    if (tid < G * NH * NN) {
      int g = tid / (NH * NN), rem = tid % (NH * NN);
      int h = rem / NN, n = rem % NN;
      const float* rp = &rus[g][h * CD];
      const unsigned short* kp = &kc[g][n][0];
      float acc = 0.f;
      for (int c = 0; c < CD; c += 4) {
        float4 rv = *(const float4*)&rp[c];
        ushort4 kv = *(const ushort4*)&kp[c];
        acc += rv.x * bf2f(kv.x) + rv.y * bf2f(kv.y) + rv.z * bf2f(kv.z) +
               rv.w * bf2f(kv.w);
      }
      scs[g][h][n] = ((msks[g] >> n) & 1u) ? acc * scale : -1e9f;
    }
    __syncthreads();
    if (tid < G * NH) {
      int g = tid / NH, h = tid % NH;
      float mx = -3.4e38f;
#pragma unroll
      for (int n = 0; n < NN; ++n) mx = fmaxf(mx, scs[g][h][n]);
      float ev[NN], s = 0.f;
#pragma unroll
      for (int n = 0; n < NN; ++n) { ev[n] = __expf(scs[g][h][n] - mx); s += ev[n]; }
      float inv = 1.f / s;
#pragma unroll
      for (int n = 0; n < NN; ++n) scs[g][h][n] = ev[n] * inv;
    }
    __syncthreads();
    for (int flat = tid; flat < G * NH * (CD / 4); flat += T) {
      int g = flat / (NH * 48), iq = flat % (NH * 48);
      int h = iq / 48, c = (iq % 48) * 4;
      const unsigned short* kp = &kc[g][0][0];
      float a0 = 0.f, a1 = 0.f, a2 = 0.f, a3 = 0.f;
#pragma unroll
      for (int n = 0; n < NN; ++n) {
        float w = scs[g][h][n];
        ushort4 kv = *(const ushort4*)&kp[n * KCS + c];
        a0 += w * bf2f(kv.x); a1 += w * bf2f(kv.y);
        a2 += w * bf2f(kv.z); a3 += w * bf2f(kv.w);
      }
      *(float4*)&rus[g][h * CD + c] = make_float4(a0, a1, a2, a3);
    }
    __syncthreads();
    {
      int j = tid & (HD - 1);
      int g = tid >> 7;
      int h = j >> 5;
      const float* wv = Wv + (l * CD) * HD + j;
      float acc = 0.f;
      for (int c = 0; c < CD; c += 4) {
        float4 uv = *(const float4*)&rus[g][h * CD + c];
        acc += uv.x * wv[(c + 0) * HD] + uv.y * wv[(c + 1) * HD] +
               uv.z * wv[(c + 2) * HD] + uv.w * wv[(c + 3) * HD];
      }
      asv[g * HD + j] = acc + bv[l * HD + j];
    }
    __syncthreads();
    {
      int j = tid & (ND - 1);
      int g = tid >> 7;
      const float* wo = Wo + (l * HD) * ND + j;
      float acc = 0.f;
      for (int c = 0; c < HD; c += 4) {
        float4 av = *(const float4*)&asv[g * HD + c];
        acc += av.x * wo[(c + 0) * ND] + av.y * wo[(c + 1) * ND] +
               av.z * wo[(c + 2) * ND] + av.w * wo[(c + 3) * ND];
      }
      rus[g][j] = acc + bo[l * ND + j];
    }
    __syncthreads();
    if (tid < G * 64) {
      int g = tid >> 6, lane = tid & 63;
      float y0 = xs[g][lane] + rus[g][lane];
      float y1 = xs[g][lane + 64] + rus[g][lane + 64];
      float s = y0 + y1, ss = y0 * y0 + y1 * y1;
#pragma unroll
      for (int off = 32; off > 0; off >>= 1) {
        s += __shfl_xor(s, off);
        ss += __shfl_xor(ss, off);
      }
      float mean = s * (1.f / ND);
      float var = ss * (1.f / ND) - mean * mean;
      float rstd = rsqrtf(var + 1e-5f);
      xs[g][lane] = (y0 - mean) * rstd * g1[l * ND + lane] + be1[l * ND + lane];
      xs[g][lane + 64] =
          (y1 - mean) * rstd * g1[l * ND + lane + 64] + be1[l * ND + lane + 64];
    }
    __syncthreads();
    {
      int j = tid;
      const float* w1p = W1 + (l * ND) * (2 * ND) + j;
      float acc0 = 0.f, acc1 = 0.f;
      for (int c = 0; c < ND; c += 4) {
        float w0 = w1p[(c + 0) * 2 * ND], wa = w1p[(c + 1) * 2 * ND],
              w2 = w1p[(c + 2) * 2 * ND], w3 = w1p[(c + 3) * 2 * ND];
        float4 x0 = *(const float4*)&xs[0][c];
        float4 x1 = *(const float4*)&xs[1][c];
        acc0 += x0.x * w0 + x0.y * wa + x0.z * w2 + x0.w * w3;
        acc1 += x1.x * w0 + x1.y * wa + x1.z * w2 + x1.w * w3;
      }
      float b1v = b1[l * 2 * ND + j];
      h1s[0][j] = fmaxf(acc0 + b1v, 0.f);
      h1s[1][j] = fmaxf(acc1 + b1v, 0.f);
    }
    __syncthreads();
    {
      int j = tid & (ND - 1);
      int g = tid >> 7;
      const float* w2p = W2 + (l * 2 * ND) * ND + j;
      float acc = 0.f;
      for (int c = 0; c < 2 * ND; c += 4) {
        float4 hv = *(const float4*)&h1s[g][c];
        acc += hv.x * w2p[(c + 0) * ND] + hv.y * w2p[(c + 1) * ND] +
               hv.z * w2p[(c + 2) * ND] + hv.w * w2p[(c + 3) * ND];
      }
      rus[g][j] = acc + b2[l * ND + j];
    }
    __syncthreads();
    if (tid < G * 64) {
      int g = tid >> 6, lane = tid & 63;
      float y0 = xs[g][lane] + rus[g][lane];
      float y1 = xs[g][lane + 64] + rus[g][lane + 64];
      float s = y0 + y1, ss = y0 * y0 + y1 * y1;
#pragma unroll
      for (int off = 32; off > 0; off >>= 1) {
        s += __shfl_xor(s, off);
        ss += __shfl_xor(ss, off);
      }
      float mean = s * (1.f / ND);
      float var = ss * (1.f / ND) - mean * mean;
      float rstd = rsqrtf(var + 1e-5f);
      xs[g][lane] = (y0 - mean) * rstd * g2[l * ND + lane] + be2[l * ND + lane];
      xs[g][lane + 64] =
          (y1 - mean) * rstd * g2[l * ND + lane + 64] + be2[l * ND + lane + 64];
    }
    __syncthreads();
  }
  if (tid < G * 64) {
    int j = tid & 63;
    int g = tid >> 6;
    const float* wc = Wc1 + j;
    float acc = 0.f;
    for (int c = 0; c < ND; c += 4) {
      float4 xv = *(const float4*)&xs[g][c];
      acc += xv.x * wc[(c + 0) * 64] + xv.y * wc[(c + 1) * 64] +
             xv.z * wc[(c + 2) * 64] + xv.w * wc[(c + 3) * 64];
    }
    ((float*)scs)[g * 64 + j] = fmaxf(acc + bc1[j], 0.f);
  }
  __syncthreads();
  if (tid < G * 64) {
    int g = tid >> 6, lane = tid & 63;
    float p = ((float*)scs)[g * 64 + lane] * Wc2[lane];
#pragma unroll
    for (int off = 32; off > 0; off >>= 1) p += __shfl_xor(p, off);
    if (lane == 0) {
      float z = p + bc2[0];
      out[b0 + g] = 1.f / (1.f + expf(-z));
    }
  }
}

extern "C" void kernel_launch(void* const* d_in, const int* in_sizes, int n_in,
                              void* d_out, int out_size, void* d_ws,
                              size_t ws_size, hipStream_t stream) {
  (void)in_sizes; (void)n_in; (void)out_size;
  const float* nf  = (const float*)d_in[0];
  const float* nbf = (const float*)d_in[1];
  const float* ntm = (const float*)d_in[2];
  const float* nbt = (const float*)d_in[3];
  const float* tf  = (const float*)d_in[4];
  const float* tp  = (const float*)d_in[5];
  const float* Wq  = (const float*)d_in[6];
  const float* bq  = (const float*)d_in[7];
  const float* Wk  = (const float*)d_in[8];
  // d_in[9] = bk: n-uniform score shift -> softmax-invariant -> dropped
  const float* Wv  = (const float*)d_in[10];
  const float* bv  = (const float*)d_in[11];
  const float* Wo  = (const float*)d_in[12];
  const float* bo  = (const float*)d_in[13];
  const float* W1  = (const float*)d_in[14];
  const float* b1  = (const float*)d_in[15];
  const float* W2  = (const float*)d_in[16];
  const float* b2  = (const float*)d_in[17];
  const float* g1  = (const float*)d_in[18];
  const float* be1 = (const float*)d_in[19];
  const float* g2  = (const float*)d_in[20];
  const float* be2 = (const float*)d_in[21];
  const float* Wc1 = (const float*)d_in[22];
  const float* bc1 = (const float*)d_in[23];
  const float* Wc2 = (const float*)d_in[24];
  const float* bc2 = (const float*)d_in[25];
  const int* mask  = (const int*)d_in[26];
  float* out = (float*)d_out;

  // Workspace layout (tier B core, 487,422,592 B — guaranteed < R6's 589MB):
  //   WF 622,592 | mb 400,000 | tqf 25.6M | yb(bf16) 25.6M | rb(f32) 307.2M
  //   (u f32 aliases rb) | ab(bf16) 25.6M | h1b(bf16) 51.2M | xfb(f32) 51.2M
  // Tier A adds kcf(bf16) 768M -> 1,255,422,592 B.
  const size_t NEED_B = 487422592ull;
  const size_t NEED_A = 1255422592ull;
  if (ws_size >= NEED_B) {
    char* w = (char*)d_ws;
    unsigned short* WF = (unsigned short*)w;
    unsigned* mb = (unsigned*)(w + 622592);
    float* tqf = (float*)(w + 1022592);
    unsigned short* yb = (unsigned short*)(w + 26622592);
    float* rb = (float*)(w + 52222592);
    unsigned short* ab = (unsigned short*)(w + 359422592);
    unsigned short* h1b = (unsigned short*)(w + 385022592);
    float* xfb = (float*)(w + 436222592);
    unsigned short* kcf = (unsigned short*)(w + 487422592);
    const int tierA = (ws_size >= NEED_A);

    conv_w<<<608, 256, 0, stream>>>(Wq, Wk, Wv, Wo, W1, W2, WF);
    prep_tq<<<25000, 256, 0, stream>>>(ntm, tf, tp, tqf);
    prep_mb<<<(BB + 255) / 256, 256, 0, stream>>>(mask, mb);
    if (tierA)
      prep_kc<<<187500, 256, 0, stream>>>(nbf, nbt, tf, tp, kcf);

    const float* xsrc = nf;
    for (int l = 0; l < NL; ++l) {
      const unsigned short* WFl = WF + (size_t)l * 155648;
      // y = [x|tq] @ Wq + bq  (bf16 out)
      gemm16<2, 0, 1><<<dim3(6250, 1), 256, 0, stream>>>(
          xsrc, ND, tqf, TD, 128, WFl, 6, 8, 0, 0, 0, bq + l * HD, yb, HD, 0);
      // r_h = y_h @ Wk_h^T  (bf16 A, f32 out)
      gemm16<3, 1, 0><<<dim3(6250, 4), 256, 0, stream>>>(
          yb, HD, nullptr, 0, 1 << 30, WFl + 24576, 1, 12, DH, 192, 12,
          nullptr, rb, 768, 0);
      // scores/softmax/u (u f32 overwrites r, element-private)
      if (tierA)
        attn_k2<<<50000, 256, 0, stream>>>(kcf, mb, rb, rb);
      else
        attn_kb<<<50000, 256, 0, stream>>>(nbf, nbt, tf, tp, mb, rb, rb);
      // a_h = u_h @ Wv_h + bv  (bf16 out)
      gemm16<1, 0, 1><<<dim3(6250, 4), 128, 0, stream>>>(
          rb, 768, nullptr, 0, 1 << 30, WFl + 49152, 6, 2, 192, DH, 12,
          bv + l * HD, ab, HD, 0);
      // x = LN1(x + a @ Wo + bo)
      gemm_ln<1><<<6250, 256, 0, stream>>>(ab, HD, 4, WFl + 73728, bo + l * ND,
                                           xsrc, g1 + l * ND, be1 + l * ND,
                                           xfb);
      // h1 = relu(x @ W1 + b1)  (bf16 out)
      gemm16<4, 0, 1><<<dim3(6250, 1), 256, 0, stream>>>(
          xfb, ND, nullptr, 0, 1 << 30, WFl + 90112, 4, 16, 0, 0, 0,
          b1 + l * 2 * ND, h1b, 2 * ND, 1);
      // x = LN2(x + h1 @ W2 + b2)
      gemm_ln<1><<<6250, 256, 0, stream>>>(h1b, 2 * ND, 8, WFl + 122880,
                                           b2 + l * ND, xfb, g2 + l * ND,
                                           be2 + l * ND, xfb);
      xsrc = xfb;
    }
    cls_k<<<25000, 256, 0, stream>>>(xfb, Wc1, bc1, Wc2, bc2, out);
  } else {
    tgat_fused<<<BB / G, T, 0, stream>>>(nf, nbf, ntm, nbt, tf, tp, Wq, bq, Wk,
                                         Wv, bv, Wo, bo, W1, b1, W2, b2, g1,
                                         be1, g2, be2, Wc1, bc1, Wc2, bc2,
                                         mask, out);
  }
}

// Round 8
// 1408.126 us; speedup vs baseline: 3.7464x; 1.2104x over previous
//
#include <hip/hip_runtime.h>

#define BB 100000
#define NN 20
#define ND 128
#define TD 64
#define CD 192
#define HD 128
#define NH 4
#define DH 32
#define NL 2

typedef __attribute__((ext_vector_type(8))) short bf16x8;
typedef __attribute__((ext_vector_type(4))) float f32x4;

static __device__ __forceinline__ float bf2f(unsigned short u) {
  return __uint_as_float(((unsigned)u) << 16);
}
static __device__ __forceinline__ unsigned short f2bf(float x) {
  unsigned b = __float_as_uint(x);
  return (unsigned short)((b + 0x7FFFu + ((b >> 16) & 1u)) >> 16);
}
static __device__ __forceinline__ bf16x8 load_a8(const float* p) {
  float4 a = *(const float4*)p, b = *(const float4*)(p + 4);
  bf16x8 r;
  r[0] = (short)f2bf(a.x); r[1] = (short)f2bf(a.y);
  r[2] = (short)f2bf(a.z); r[3] = (short)f2bf(a.w);
  r[4] = (short)f2bf(b.x); r[5] = (short)f2bf(b.y);
  r[6] = (short)f2bf(b.z); r[7] = (short)f2bf(b.w);
  return r;
}

// ---------------------------------------------------------------------------
// MFMA pipeline (16x16x32 bf16). Fragment layouts HW-verified (m89).
// Per-layer WF layout (u16 units, 512/tile): tiles 0-47 Wq[kt*8+nt],
// 48-95 Wk^T[h*12+nt], 96-143 Wv[h*12+kt*2+nt], 144-175 Wo[kt*8+nt],
// 176-239 W1[kt*16+nt], 240-303 W2[kt*8+nt].  Layer stride 155,648 u16.
// R8: r & u stored bf16 (u bit-identical: consumer f2bf'd anyway; r adds one
// bf16 rounding pre-scores). prep_kc folded into layer-1 attn (writes kcf as
// a side product); layer-2 attn reads kcf.
// ---------------------------------------------------------------------------

__global__ __launch_bounds__(256) void conv_w(
    const float* __restrict__ Wq, const float* __restrict__ Wk,
    const float* __restrict__ Wv, const float* __restrict__ Wo,
    const float* __restrict__ W1, const float* __restrict__ W2,
    unsigned short* __restrict__ WF) {
  int t = blockIdx.x;
  int l = t / 304, tt = t % 304;
#pragma unroll
  for (int e = 0; e < 2; ++e) {
    int idx = threadIdx.x * 2 + e;      // 0..511 element within tile
    int lane = idx >> 3, j = idx & 7;
    int wk = ((lane >> 4) << 3) + j;    // within-tile k 0..31
    int c16 = lane & 15;
    float v;
    if (tt < 48) {                      // Wq [192x128]
      int kt = tt >> 3, n2 = tt & 7;
      v = Wq[((size_t)l * CD + kt * 32 + wk) * HD + n2 * 16 + c16];
    } else if (tt < 96) {               // Wk^T per head [32x192]
      int t2 = tt - 48; int h = t2 / 12, n2 = t2 % 12;
      v = Wk[((size_t)l * CD + n2 * 16 + c16) * HD + h * 32 + wk];
    } else if (tt < 144) {              // Wv per head [192x32]
      int t2 = tt - 96; int h = t2 / 12, r2 = t2 % 12, kt = r2 >> 1, n2 = r2 & 1;
      v = Wv[((size_t)l * CD + kt * 32 + wk) * HD + h * 32 + n2 * 16 + c16];
    } else if (tt < 176) {              // Wo [128x128]
      int t2 = tt - 144; int kt = t2 >> 3, n2 = t2 & 7;
      v = Wo[((size_t)l * HD + kt * 32 + wk) * ND + n2 * 16 + c16];
    } else if (tt < 240) {              // W1 [128x256]
      int t2 = tt - 176; int kt = t2 >> 4, n2 = t2 & 15;
      v = W1[((size_t)l * ND + kt * 32 + wk) * (2 * ND) + n2 * 16 + c16];
    } else {                            // W2 [256x128]
      int t2 = tt - 240; int kt = t2 >> 3, n2 = t2 & 7;
      v = W2[((size_t)l * 2 * ND + kt * 32 + wk) * ND + n2 * 16 + c16];
    }
    WF[(size_t)l * 155648 + (size_t)tt * 512 + idx] = f2bf(v);
  }
}

__global__ __launch_bounds__(256) void prep_tq(
    const float* __restrict__ ntime, const float* __restrict__ tf,
    const float* __restrict__ tp, float* __restrict__ tqf) {
  int i = blockIdx.x * 256 + threadIdx.x;  // 0..6.4M
  int b = i >> 6, j = i & 63;
  tqf[i] = __cosf(ntime[b] * tf[j] + tp[j]);
}

__global__ __launch_bounds__(256) void prep_mb(const int* __restrict__ mask,
                                               unsigned* __restrict__ mb) {
  int e = blockIdx.x * 256 + threadIdx.x;
  if (e < BB) {
    unsigned m = 0;
    for (int n = 0; n < NN; ++n)
      m |= (mask[(size_t)e * NN + n] != 0 ? 1u : 0u) << n;
    mb[e] = m;
  }
}

// Generic 16-row-block GEMM. ABF: A bf16; OBF: out bf16 (f2bf at store ==
// f2bf at consumer load). A2 concat source always f32.
template <int TN, int ABF, int OBF>
__global__ __launch_bounds__(256) void gemm16(
    const void* __restrict__ A, int lda,
    const float* __restrict__ A2, int lda2, int ksplit,
    const unsigned short* __restrict__ BF,
    int ktiles, int ntiles, int aKoffMul, int cColMul, int segBMul,
    const float* __restrict__ bias,
    void* __restrict__ C, int ldc, int relu) {
  const int tid = threadIdx.x;
  const int wv = tid >> 6, lane = tid & 63;
  const int NW = blockDim.x >> 6;
  const int m0 = blockIdx.x << 4;
  const int seg = blockIdx.y;
  const int arow = m0 + (lane & 15);
  const int kgrp = (lane >> 4) << 3;
  const int aK = seg * aKoffMul;
  const unsigned short* Bseg = BF + (size_t)seg * segBMul * 512;
  f32x4 acc[TN];
#pragma unroll
  for (int i = 0; i < TN; ++i) acc[i] = f32x4{0.f, 0.f, 0.f, 0.f};
  for (int kt = 0; kt < ktiles; ++kt) {
    bf16x8 af;
    if (kt * 32 >= ksplit) {
      af = load_a8(A2 + (size_t)arow * lda2 + (kt * 32 - ksplit) + kgrp);
    } else if (ABF) {
      af = *(const bf16x8*)((const unsigned short*)A + (size_t)arow * lda + aK +
                            kt * 32 + kgrp);
    } else {
      af = load_a8((const float*)A + (size_t)arow * lda + aK + kt * 32 + kgrp);
    }
#pragma unroll
    for (int i = 0; i < TN; ++i) {
      int nt = wv + NW * i;
      bf16x8 bf = *(const bf16x8*)(Bseg + (((size_t)(kt * ntiles + nt)) << 9) +
                                   (lane << 3));
      acc[i] = __builtin_amdgcn_mfma_f32_16x16x32_bf16(af, bf, acc[i], 0, 0, 0);
    }
  }
  const int crow = m0 + ((lane >> 4) << 2);
#pragma unroll
  for (int i = 0; i < TN; ++i) {
    int nt = wv + NW * i;
    int col = seg * cColMul + nt * 16 + (lane & 15);
    float bv = bias ? bias[col] : 0.f;
#pragma unroll
    for (int rr = 0; rr < 4; ++rr) {
      float v = acc[i][rr] + bv;
      if (relu) v = fmaxf(v, 0.f);
      if (OBF)
        ((unsigned short*)C)[(size_t)(crow + rr) * ldc + col] = f2bf(v);
      else
        ((float*)C)[(size_t)(crow + rr) * ldc + col] = v;
    }
  }
}

// GEMM (N=128) + bias + residual + LayerNorm fused epilogue -> xout f32.
template <int ABF>
__global__ __launch_bounds__(256) void gemm_ln(
    const void* __restrict__ A, int lda, int ktiles,
    const unsigned short* __restrict__ BF,
    const float* __restrict__ bias, const float* __restrict__ res,
    const float* __restrict__ gamma, const float* __restrict__ beta,
    float* __restrict__ xout) {
  __shared__ float Cs[16][132];
  const int tid = threadIdx.x;
  const int wv = tid >> 6, lane = tid & 63;
  const int m0 = blockIdx.x << 4;
  const int arow = m0 + (lane & 15);
  const int kgrp = (lane >> 4) << 3;
  const int nt0 = wv, nt1 = wv + 4;
  f32x4 acc0 = {0.f, 0.f, 0.f, 0.f}, acc1 = {0.f, 0.f, 0.f, 0.f};
  for (int kt = 0; kt < ktiles; ++kt) {
    bf16x8 af;
    if (ABF)
      af = *(const bf16x8*)((const unsigned short*)A + (size_t)arow * lda +
                            kt * 32 + kgrp);
    else
      af = load_a8((const float*)A + (size_t)arow * lda + kt * 32 + kgrp);
    bf16x8 b0 = *(const bf16x8*)(BF + (((size_t)(kt * 8 + nt0)) << 9) + (lane << 3));
    bf16x8 b1 = *(const bf16x8*)(BF + (((size_t)(kt * 8 + nt1)) << 9) + (lane << 3));
    acc0 = __builtin_amdgcn_mfma_f32_16x16x32_bf16(af, b0, acc0, 0, 0, 0);
    acc1 = __builtin_amdgcn_mfma_f32_16x16x32_bf16(af, b1, acc1, 0, 0, 0);
  }
  {
    const int lrow = (lane >> 4) << 2;
    int c0 = nt0 * 16 + (lane & 15), c1 = nt1 * 16 + (lane & 15);
    float bv0 = bias[c0], bv1 = bias[c1];
#pragma unroll
    for (int rr = 0; rr < 4; ++rr) {
      Cs[lrow + rr][c0] = acc0[rr] + bv0;
      Cs[lrow + rr][c1] = acc1[rr] + bv1;
    }
  }
  __syncthreads();
#pragma unroll
  for (int rr = 0; rr < 4; ++rr) {
    int rw = wv * 4 + rr;
    size_t grow = (size_t)(m0 + rw) * ND;
    float y0 = Cs[rw][lane] + res[grow + lane];
    float y1 = Cs[rw][lane + 64] + res[grow + lane + 64];
    float s = y0 + y1, ss = y0 * y0 + y1 * y1;
#pragma unroll
    for (int off = 32; off > 0; off >>= 1) {
      s += __shfl_xor(s, off);
      ss += __shfl_xor(ss, off);
    }
    float mean = s * (1.f / ND);
    float var = ss * (1.f / ND) - mean * mean;
    float rstd = rsqrtf(var + 1e-5f);
    xout[grow + lane] = (y0 - mean) * rstd * gamma[lane] + beta[lane];
    xout[grow + lane + 64] =
        (y1 - mean) * rstd * gamma[lane + 64] + beta[lane + 64];
  }
}

// Attention, 2 elements/block. r,u bf16 (u aliases r: element-private, r
// staged to LDS before u writes). KCSRC: 0 = compute kc in-kernel (tier B),
// 1 = compute kc AND write kcf (tier A layer 1), 2 = read kcf (tier A L2+).
template <int KCSRC>
__global__ __launch_bounds__(256) void attn_t(
    const float* __restrict__ nbf, const float* __restrict__ nbt,
    const float* __restrict__ tf, const float* __restrict__ tp,
    const unsigned short* __restrict__ kcf_in,
    unsigned short* __restrict__ kcf_out,
    const unsigned* __restrict__ mb, const unsigned short* __restrict__ r,
    unsigned short* __restrict__ u) {
  __shared__ __align__(16) unsigned short kcb[2][NN][200];
  __shared__ __align__(16) float rs[2][768];
  __shared__ __align__(16) float scs[2][NH][NN];
  __shared__ unsigned msks[2];
  const int tid = threadIdx.x;
  const size_t e0 = (size_t)blockIdx.x * 2;

  // stage r (bf16 -> f32 LDS): 1536 u16 = 192 x uint4
  if (tid < 192) {
    uint4 v = *(const uint4*)(r + e0 * 768 + tid * 8);
    const unsigned short* pv = (const unsigned short*)&v;
    float* dst = &rs[0][0] + tid * 8;
#pragma unroll
    for (int k = 0; k < 8; ++k) dst[k] = bf2f(pv[k]);
  }
  if (KCSRC == 2) {
    // load kc: 2*20*192 u16 = 960 x 8-u16 chunks
    for (int i = tid; i < 960; i += 256) {
      int el = i / 480, rem = i % 480;
      int n = rem / 24, q = rem % 24;
      *(uint4*)&kcb[el][n][q * 8] =
          *(const uint4*)&kcf_in[((e0 + el) * NN + n) * 192 + q * 8];
    }
  } else {
    for (int i = tid; i < 2 * NN * 32; i += 256) {
      int el = i / (NN * 32), rem = i % (NN * 32);
      int n = rem >> 5, cq = rem & 31;
      float4 v = *(const float4*)&nbf[((e0 + el) * NN + n) * ND + cq * 4];
      ushort4 o;
      o.x = f2bf(v.x); o.y = f2bf(v.y); o.z = f2bf(v.z); o.w = f2bf(v.w);
      *(ushort4*)&kcb[el][n][cq * 4] = o;
      if (KCSRC == 1)
        *(ushort4*)&kcf_out[((e0 + el) * NN + n) * 192 + cq * 4] = o;
    }
    for (int i = tid; i < 2 * NN * 32; i += 256) {
      int el = i / (NN * 32), rem = i % (NN * 32);
      int n = rem >> 5, jp = (rem & 31) * 2;
      float t = nbt[(e0 + el) * NN + n];
      unsigned a = f2bf(__cosf(t * tf[jp] + tp[jp]));
      unsigned b = f2bf(__cosf(t * tf[jp + 1] + tp[jp + 1]));
      unsigned w = a | (b << 16);
      *(unsigned*)&kcb[el][n][ND + jp] = w;
      if (KCSRC == 1)
        *(unsigned*)&kcf_out[((e0 + el) * NN + n) * 192 + ND + jp] = w;
    }
  }
  if (tid < 2) msks[tid] = mb[e0 + tid];
  __syncthreads();
  if (tid < 2 * NH * NN) {
    int el = tid / (NH * NN), rem = tid % (NH * NN);
    int h = rem / NN, n = rem % NN;
    const float* rp = &rs[el][h * CD];
    const unsigned short* kp = &kcb[el][n][0];
    float acc = 0.f;
    for (int c = 0; c < CD; c += 4) {
      float4 rv = *(const float4*)&rp[c];
      ushort4 kv = *(const ushort4*)&kp[c];
      acc += rv.x * bf2f(kv.x) + rv.y * bf2f(kv.y) + rv.z * bf2f(kv.z) +
             rv.w * bf2f(kv.w);
    }
    scs[el][h][n] =
        ((msks[el] >> n) & 1u) ? acc * 0.17677669529663687f : -1e9f;
  }
  __syncthreads();
  if (tid < 2 * NH) {
    int el = tid >> 2, h = tid & 3;
    float mx = -3.4e38f;
#pragma unroll
    for (int n = 0; n < NN; ++n) mx = fmaxf(mx, scs[el][h][n]);
    float ev[NN], s = 0.f;
#pragma unroll
    for (int n = 0; n < NN; ++n) { ev[n] = __expf(scs[el][h][n] - mx); s += ev[n]; }
    float inv = 1.f / s;
#pragma unroll
    for (int n = 0; n < NN; ++n) scs[el][h][n] = ev[n] * inv;
  }
  __syncthreads();
  for (int i = tid; i < 2 * NH * (CD / 4); i += 256) {  // 384 quads
    int el = i / (NH * 48), rem = i % (NH * 48);
    int h = rem / 48, cq = (rem % 48) * 4;
    float a0 = 0.f, a1 = 0.f, a2 = 0.f, a3 = 0.f;
#pragma unroll
    for (int n = 0; n < NN; ++n) {
      float w = scs[el][h][n];
      ushort4 kv = *(const ushort4*)&kcb[el][n][cq];
      a0 += w * bf2f(kv.x); a1 += w * bf2f(kv.y);
      a2 += w * bf2f(kv.z); a3 += w * bf2f(kv.w);
    }
    ushort4 o;
    o.x = f2bf(a0); o.y = f2bf(a1); o.z = f2bf(a2); o.w = f2bf(a3);
    *(ushort4*)&u[(e0 + el) * 768 + h * 192 + cq] = o;
  }
}

__global__ __launch_bounds__(256) void cls_k(
    const float* __restrict__ xf, const float* __restrict__ Wc1,
    const float* __restrict__ bc1, const float* __restrict__ Wc2,
    const float* __restrict__ bc2, float* __restrict__ out) {
  __shared__ float xsh[4][128];
  const int tid = threadIdx.x;
  const size_t e0 = (size_t)blockIdx.x * 4;
  for (int i = tid; i < 512; i += 256) xsh[0][i] = xf[e0 * 128 + i];
  __syncthreads();
  int el = tid >> 6, lane = tid & 63;
  float acc = 0.f;
  for (int c = 0; c < 128; ++c) acc += xsh[el][c] * Wc1[c * 64 + lane];
  acc = fmaxf(acc + bc1[lane], 0.f);
  float p = acc * Wc2[lane];
#pragma unroll
  for (int off = 32; off > 0; off >>= 1) p += __shfl_xor(p, off);
  if (lane == 0) out[e0 + el] = 1.f / (1.f + expf(-(p + bc2[0])));
}

// ---------------------------------------------------------------------------
// Tier C fallback (R5 fused kernel) if workspace is tiny.
// ---------------------------------------------------------------------------
#define G 2
#define T 256
#define KCS 196
#define RUS 772

__global__ __launch_bounds__(T, 4) void tgat_fused(
    const float* __restrict__ nf, const float* __restrict__ nbf,
    const float* __restrict__ nt, const float* __restrict__ nbt,
    const float* __restrict__ tf, const float* __restrict__ tp,
    const float* __restrict__ Wq, const float* __restrict__ bq,
    const float* __restrict__ Wk,
    const float* __restrict__ Wv, const float* __restrict__ bv,
    const float* __restrict__ Wo, const float* __restrict__ bo,
    const float* __restrict__ W1, const float* __restrict__ b1,
    const float* __restrict__ W2, const float* __restrict__ b2,
    const float* __restrict__ g1, const float* __restrict__ be1,
    const float* __restrict__ g2, const float* __restrict__ be2,
    const float* __restrict__ Wc1, const float* __restrict__ bc1,
    const float* __restrict__ Wc2, const float* __restrict__ bc2,
    const int* __restrict__ mask,
    float* __restrict__ out) {
  __shared__ __align__(16) unsigned short kc[G][NN][KCS];
  __shared__ __align__(16) float xs[G][ND];
  __shared__ __align__(16) float tqs[G][TD];
  __shared__ __align__(16) float ys[G][HD];
  __shared__ __align__(16) float rus[G][RUS];
  __shared__ __align__(16) float scs[G][NH][NN];
  __shared__ __align__(16) float h1s[G][2 * ND];
  __shared__ __align__(16) unsigned msks[G];
  float* asv = &h1s[0][0];
  const int tid = threadIdx.x;
  const int b0 = blockIdx.x * G;
  {
    int g = tid >> 7, j = tid & 127;
    xs[g][j] = nf[(b0 + g) * ND + j];
  }
  if (tid < G * TD) {
    int g = tid >> 6, j = tid & 63;
    tqs[g][j] = __cosf(nt[b0 + g] * tf[j] + tp[j]);
  }
  if (tid < G) {
    unsigned m = 0;
    for (int n = 0; n < NN; ++n)
      m |= (mask[(b0 + tid) * NN + n] != 0 ? 1u : 0u) << n;
    msks[tid] = m;
  }
  for (int idx = tid; idx < G * NN * (ND / 4); idx += T) {
    int g = idx / (NN * 32), rem = idx % (NN * 32);
    int n = rem >> 5, cq = rem & 31;
    float4 v = *(const float4*)&nbf[(((b0 + g) * NN + n) * ND) + cq * 4];
    ushort4 o;
    o.x = f2bf(v.x); o.y = f2bf(v.y); o.z = f2bf(v.z); o.w = f2bf(v.w);
    *(ushort4*)&kc[g][n][cq * 4] = o;
  }
  for (int idx = tid; idx < G * NN * TD; idx += T) {
    int g = idx / (NN * TD), rem = idx % (NN * TD);
    int n = rem >> 6, j = rem & 63;
    kc[g][n][ND + j] = f2bf(__cosf(nbt[(b0 + g) * NN + n] * tf[j] + tp[j]));
  }
  __syncthreads();
  const float scale = 0.17677669529663687f;
  for (int l = 0; l < NL; ++l) {
    {
      int g = tid >> 7, j = tid & 127;
      const float* wq = Wq + (l * CD) * HD + j;
      float acc = bq[l * HD + j];
      for (int c = 0; c < CD; c += 4) {
        float4 qv = (c < ND) ? *(const float4*)&xs[g][c]
                             : *(const float4*)&tqs[g][c - ND];
        acc += qv.x * wq[(c + 0) * HD] + qv.y * wq[(c + 1) * HD] +
               qv.z * wq[(c + 2) * HD] + qv.w * wq[(c + 3) * HD];
      }
      ys[g][j] = acc;
    }
    __syncthreads();
    for (int rep = 0; rep < 3; ++rep) {
      int i = rep * T + tid;
      int h = i / CD;
      int c2 = i - h * CD;
      const float* wk = Wk + (l * CD + c2) * HD + h * DH;
      const float* yp0 = &ys[0][h * DH];
      const float* yp1 = &ys[1][h * DH];
      float a0 = 0.f, a1 = 0.f;
#pragma unroll
      for (int d = 0; d < DH; d += 4) {
        float4 w4 = *(const float4*)&wk[d];
        float4 y0 = *(const float4*)&yp0[d];
        float4 y1 = *(const float4*)&yp1[d];
        a0 += y0.x * w4.x + y0.y * w4.y + y0.z * w4.z + y0.w * w4.w;
        a1 += y1.x * w4.x + y1.y * w4.y + y1.z * w4.z + y1.w * w4.w;
      }
      rus[0][i] = a0;
      rus[1][i] = a1;
    }
    __syncthreads();
    if (tid < G * NH * NN) {
      int g = tid / (NH * NN), rem = tid % (NH * NN);
      int h = rem / NN, n = rem % NN;
      const float* rp = &rus[g][h * CD];
      const unsigned short* kp = &kc[g][n][0];
      float acc = 0.f;
      for (int c = 0; c < CD; c += 4) {
        float4 rv = *(const float4*)&rp[c];
        ushort4 kv = *(const ushort4*)&kp[c];
        acc += rv.x * bf2f(kv.x) + rv.y * bf2f(kv.y) + rv.z * bf2f(kv.z) +
               rv.w * bf2f(kv.w);
      }
      scs[g][h][n] = ((msks[g] >> n) & 1u) ? acc * scale : -1e9f;
    }
    __syncthreads();
    if (tid < G * NH) {
      int g = tid / NH, h = tid % NH;
      float mx = -3.4e38f;
#pragma unroll
      for (int n = 0; n < NN; ++n) mx = fmaxf(mx, scs[g][h][n]);
      float ev[NN], s = 0.f;
#pragma unroll
      for (int n = 0; n < NN; ++n) { ev[n] = __expf(scs[g][h][n] - mx); s += ev[n]; }
      float inv = 1.f / s;
#pragma unroll
      for (int n = 0; n < NN; ++n) scs[g][h][n] = ev[n] * inv;
    }
    __syncthreads();
    for (int flat = tid; flat < G * NH * (CD / 4); flat += T) {
      int g = flat / (NH * 48), iq = flat % (NH * 48);
      int h = iq / 48, c = (iq % 48) * 4;
      const unsigned short* kp = &kc[g][0][0];
      float a0 = 0.f, a1 = 0.f, a2 = 0.f, a3 = 0.f;
#pragma unroll
      for (int n = 0; n < NN; ++n) {
        float w = scs[g][h][n];
        ushort4 kv = *(const ushort4*)&kp[n * KCS + c];
        a0 += w * bf2f(kv.x); a1 += w * bf2f(kv.y);
        a2 += w * bf2f(kv.z); a3 += w * bf2f(kv.w);
      }
      *(float4*)&rus[g][h * CD + c] = make_float4(a0, a1, a2, a3);
    }
    __syncthreads();
    {
      int j = tid & (HD - 1);
      int g = tid >> 7;
      int h = j >> 5;
      const float* wv = Wv + (l * CD) * HD + j;
      float acc = 0.f;
      for (int c = 0; c < CD; c += 4) {
        float4 uv = *(const float4*)&rus[g][h * CD + c];
        acc += uv.x * wv[(c + 0) * HD] + uv.y * wv[(c + 1) * HD] +
               uv.z * wv[(c + 2) * HD] + uv.w * wv[(c + 3) * HD];
      }
      asv[g * HD + j] = acc + bv[l * HD + j];
    }
    __syncthreads();
    {
      int j = tid & (ND - 1);
      int g = tid >> 7;
      const float* wo = Wo + (l * HD) * ND + j;
      float acc = 0.f;
      for (int c = 0; c < HD; c += 4) {
        float4 av = *(const float4*)&asv[g * HD + c];
        acc += av.x * wo[(c + 0) * ND] + av.y * wo[(c + 1) * ND] +
               av.z * wo[(c + 2) * ND] + av.w * wo[(c + 3) * ND];
      }
      rus[g][j] = acc + bo[l * ND + j];
    }
    __syncthreads();
    if (tid < G * 64) {
      int g = tid >> 6, lane = tid & 63;
      float y0 = xs[g][lane] + rus[g][lane];
      float y1 = xs[g][lane + 64] + rus[g][lane + 64];
      float s = y0 + y1, ss = y0 * y0 + y1 * y1;
#pragma unroll
      for (int off = 32; off > 0; off >>= 1) {
        s += __shfl_xor(s, off);
        ss += __shfl_xor(ss, off);
      }
      float mean = s * (1.f / ND);
      float var = ss * (1.f / ND) - mean * mean;
      float rstd = rsqrtf(var + 1e-5f);
      xs[g][lane] = (y0 - mean) * rstd * g1[l * ND + lane] + be1[l * ND + lane];
      xs[g][lane + 64] =
          (y1 - mean) * rstd * g1[l * ND + lane + 64] + be1[l * ND + lane + 64];
    }
    __syncthreads();
    {
      int j = tid;
      const float* w1p = W1 + (l * ND) * (2 * ND) + j;
      float acc0 = 0.f, acc1 = 0.f;
      for (int c = 0; c < ND; c += 4) {
        float w0 = w1p[(c + 0) * 2 * ND], wa = w1p[(c + 1) * 2 * ND],
              w2 = w1p[(c + 2) * 2 * ND], w3 = w1p[(c + 3) * 2 * ND];
        float4 x0 = *(const float4*)&xs[0][c];
        float4 x1 = *(const float4*)&xs[1][c];
        acc0 += x0.x * w0 + x0.y * wa + x0.z * w2 + x0.w * w3;
        acc1 += x1.x * w0 + x1.y * wa + x1.z * w2 + x1.w * w3;
      }
      float b1v = b1[l * 2 * ND + j];
      h1s[0][j] = fmaxf(acc0 + b1v, 0.f);
      h1s[1][j] = fmaxf(acc1 + b1v, 0.f);
    }
    __syncthreads();
    {
      int j = tid & (ND - 1);
      int g = tid >> 7;
      const float* w2p = W2 + (l * 2 * ND) * ND + j;
      float acc = 0.f;
      for (int c = 0; c < 2 * ND; c += 4) {
        float4 hv = *(const float4*)&h1s[g][c];
        acc += hv.x * w2p[(c + 0) * ND] + hv.y * w2p[(c + 1) * ND] +
               hv.z * w2p[(c + 2) * ND] + hv.w * w2p[(c + 3) * ND];
      }
      rus[g][j] = acc + b2[l * ND + j];
    }
    __syncthreads();
    if (tid < G * 64) {
      int g = tid >> 6, lane = tid & 63;
      float y0 = xs[g][lane] + rus[g][lane];
      float y1 = xs[g][lane + 64] + rus[g][lane + 64];
      float s = y0 + y1, ss = y0 * y0 + y1 * y1;
#pragma unroll
      for (int off = 32; off > 0; off >>= 1) {
        s += __shfl_xor(s, off);
        ss += __shfl_xor(ss, off);
      }
      float mean = s * (1.f / ND);
      float var = ss * (1.f / ND) - mean * mean;
      float rstd = rsqrtf(var + 1e-5f);
      xs[g][lane] = (y0 - mean) * rstd * g2[l * ND + lane] + be2[l * ND + lane];
      xs[g][lane + 64] =
          (y1 - mean) * rstd * g2[l * ND + lane + 64] + be2[l * ND + lane + 64];
    }
    __syncthreads();
  }
  if (tid < G * 64) {
    int j = tid & 63;
    int g = tid >> 6;
    const float* wc = Wc1 + j;
    float acc = 0.f;
    for (int c = 0; c < ND; c += 4) {
      float4 xv = *(const float4*)&xs[g][c];
      acc += xv.x * wc[(c + 0) * 64] + xv.y * wc[(c + 1) * 64] +
             xv.z * wc[(c + 2) * 64] + xv.w * wc[(c + 3) * 64];
    }
    ((float*)scs)[g * 64 + j] = fmaxf(acc + bc1[j], 0.f);
  }
  __syncthreads();
  if (tid < G * 64) {
    int g = tid >> 6, lane = tid & 63;
    float p = ((float*)scs)[g * 64 + lane] * Wc2[lane];
#pragma unroll
    for (int off = 32; off > 0; off >>= 1) p += __shfl_xor(p, off);
    if (lane == 0) {
      float z = p + bc2[0];
      out[b0 + g] = 1.f / (1.f + expf(-z));
    }
  }
}

extern "C" void kernel_launch(void* const* d_in, const int* in_sizes, int n_in,
                              void* d_out, int out_size, void* d_ws,
                              size_t ws_size, hipStream_t stream) {
  (void)in_sizes; (void)n_in; (void)out_size;
  const float* nf  = (const float*)d_in[0];
  const float* nbf = (const float*)d_in[1];
  const float* ntm = (const float*)d_in[2];
  const float* nbt = (const float*)d_in[3];
  const float* tf  = (const float*)d_in[4];
  const float* tp  = (const float*)d_in[5];
  const float* Wq  = (const float*)d_in[6];
  const float* bq  = (const float*)d_in[7];
  const float* Wk  = (const float*)d_in[8];
  // d_in[9] = bk: n-uniform score shift -> softmax-invariant -> dropped
  const float* Wv  = (const float*)d_in[10];
  const float* bv  = (const float*)d_in[11];
  const float* Wo  = (const float*)d_in[12];
  const float* bo  = (const float*)d_in[13];
  const float* W1  = (const float*)d_in[14];
  const float* b1  = (const float*)d_in[15];
  const float* W2  = (const float*)d_in[16];
  const float* b2  = (const float*)d_in[17];
  const float* g1  = (const float*)d_in[18];
  const float* be1 = (const float*)d_in[19];
  const float* g2  = (const float*)d_in[20];
  const float* be2 = (const float*)d_in[21];
  const float* Wc1 = (const float*)d_in[22];
  const float* bc1 = (const float*)d_in[23];
  const float* Wc2 = (const float*)d_in[24];
  const float* bc2 = (const float*)d_in[25];
  const int* mask  = (const int*)d_in[26];
  float* out = (float*)d_out;

  // Workspace (bytes):
  //   WF      0 ..      622,592
  //   mb        .. + 400,000   =   1,022,592
  //   tqf       .. + 25.6M     =  26,622,592
  //   yb(bf16)  .. + 25.6M     =  52,222,592
  //   rb(bf16)  .. + 153.6M    = 205,822,592   (u aliases rb)
  //   ab(bf16)  .. + 25.6M     = 231,422,592
  //   h1b(bf16) .. + 51.2M     = 282,622,592
  //   xfb(f32)  .. + 51.2M     = 333,822,592   <- NEED_B
  //   kcf(bf16) .. + 768M      = 1,101,822,592 <- NEED_A
  const size_t NEED_B = 333822592ull;
  const size_t NEED_A = 1101822592ull;
  if (ws_size >= NEED_B) {
    char* w = (char*)d_ws;
    unsigned short* WF = (unsigned short*)w;
    unsigned* mb = (unsigned*)(w + 622592);
    float* tqf = (float*)(w + 1022592);
    unsigned short* yb = (unsigned short*)(w + 26622592);
    unsigned short* rb = (unsigned short*)(w + 52222592);
    unsigned short* ab = (unsigned short*)(w + 205822592);
    unsigned short* h1b = (unsigned short*)(w + 231422592);
    float* xfb = (float*)(w + 282622592);
    unsigned short* kcf = (unsigned short*)(w + 333822592);
    const int tierA = (ws_size >= NEED_A);

    conv_w<<<608, 256, 0, stream>>>(Wq, Wk, Wv, Wo, W1, W2, WF);
    prep_tq<<<25000, 256, 0, stream>>>(ntm, tf, tp, tqf);
    prep_mb<<<(BB + 255) / 256, 256, 0, stream>>>(mask, mb);

    const float* xsrc = nf;
    for (int l = 0; l < NL; ++l) {
      const unsigned short* WFl = WF + (size_t)l * 155648;
      // y = [x|tq] @ Wq + bq  (bf16 out)
      gemm16<2, 0, 1><<<dim3(6250, 1), 256, 0, stream>>>(
          xsrc, ND, tqf, TD, 128, WFl, 6, 8, 0, 0, 0, bq + l * HD, yb, HD, 0);
      // r_h = y_h @ Wk_h^T  (bf16 in, bf16 out)
      gemm16<3, 1, 1><<<dim3(6250, 4), 256, 0, stream>>>(
          yb, HD, nullptr, 0, 1 << 30, WFl + 24576, 1, 12, DH, 192, 12,
          nullptr, rb, 768, 0);
      // scores/softmax/u (u bf16 overwrites r, element-private)
      if (tierA) {
        if (l == 0)
          attn_t<1><<<50000, 256, 0, stream>>>(nbf, nbt, tf, tp, nullptr, kcf,
                                               mb, rb, rb);
        else
          attn_t<2><<<50000, 256, 0, stream>>>(nbf, nbt, tf, tp, kcf, nullptr,
                                               mb, rb, rb);
      } else {
        attn_t<0><<<50000, 256, 0, stream>>>(nbf, nbt, tf, tp, nullptr,
                                             nullptr, mb, rb, rb);
      }
      // a_h = u_h @ Wv_h + bv  (bf16 in, bf16 out)
      gemm16<1, 1, 1><<<dim3(6250, 4), 128, 0, stream>>>(
          rb, 768, nullptr, 0, 1 << 30, WFl + 49152, 6, 2, 192, DH, 12,
          bv + l * HD, ab, HD, 0);
      // x = LN1(x + a @ Wo + bo)
      gemm_ln<1><<<6250, 256, 0, stream>>>(ab, HD, 4, WFl + 73728, bo + l * ND,
                                           xsrc, g1 + l * ND, be1 + l * ND,
                                           xfb);
      // h1 = relu(x @ W1 + b1)  (bf16 out)
      gemm16<4, 0, 1><<<dim3(6250, 1), 256, 0, stream>>>(
          xfb, ND, nullptr, 0, 1 << 30, WFl + 90112, 4, 16, 0, 0, 0,
          b1 + l * 2 * ND, h1b, 2 * ND, 1);
      // x = LN2(x + h1 @ W2 + b2)
      gemm_ln<1><<<6250, 256, 0, stream>>>(h1b, 2 * ND, 8, WFl + 122880,
                                           b2 + l * ND, xfb, g2 + l * ND,
                                           be2 + l * ND, xfb);
      xsrc = xfb;
    }
    cls_k<<<25000, 256, 0, stream>>>(xfb, Wc1, bc1, Wc2, bc2, out);
  } else {
    tgat_fused<<<BB / G, T, 0, stream>>>(nf, nbf, ntm, nbt, tf, tp, Wq, bq, Wk,
                                         Wv, bv, Wo, bo, W1, b1, W2, b2, g1,
                                         be1, g2, be2, Wc1, bc1, Wc2, bc2,
                                         mask, out);
  }
}